// Round 1
// baseline (19478.307 us; speedup 1.0000x reference)
//
#include <hip/hip_runtime.h>

#define N_NODES 100000
#define N_REL 4
#define N_EDGES 800000
#define HIDDEN 128
#define N_LAYERS 3

// ---- degree histogram: x[n][r] = # edges in relation r with dst==n ----
__global__ void deg_kernel(const int* __restrict__ ei, float* __restrict__ x) {
    int e = blockIdx.x * blockDim.x + threadIdx.x;
    int r = blockIdx.y;
    if (e >= N_EDGES) return;
    int d = ei[(size_t)r * 2 * N_EDGES + N_EDGES + e];
    atomicAdd(&x[(size_t)d * N_REL + r], 1.0f);
}

// ---- h = tanh(x @ W_in), x: N x 4, W_in: 4 x 128 ----
__global__ void hinit_kernel(const float* __restrict__ x, const float* __restrict__ Win,
                             float* __restrict__ h) {
    int t = blockIdx.x * blockDim.x + threadIdx.x;
    if (t >= N_NODES * HIDDEN) return;
    int n = t >> 7, j = t & 127;
    float s = 0.f;
#pragma unroll
    for (int r = 0; r < N_REL; ++r) s += x[n * N_REL + r] * Win[r * HIDDEN + j];
    h[t] = tanhf(s);
}

// ---- agg[dst] += h[src] over edges; 32 threads per edge, float4 per thread ----
__global__ void scatter_kernel(const int* __restrict__ src, const int* __restrict__ dst,
                               const float* __restrict__ h, float* __restrict__ agg) {
    long long tid = (long long)blockIdx.x * blockDim.x + threadIdx.x;
    int e = (int)(tid >> 5), q = (int)(tid & 31);
    if (e >= N_EDGES) return;
    int s = src[e], d = dst[e];
    float4 v = ((const float4*)(h + (size_t)s * HIDDEN))[q];
    float* a = agg + (size_t)d * HIDDEN + q * 4;
    atomicAdd(a + 0, v.x);
    atomicAdd(a + 1, v.y);
    atomicAdd(a + 2, v.z);
    atomicAdd(a + 3, v.w);
}

// ---- out[n][j] (op)= tanh(sum_k in[n][k] * W[k][j]) ----
// MODE 0: out = base + tanh(...)   (comb init from h)
// MODE 1: out += tanh(...)         (comb accumulate)
// MODE 2: out = tanh(...)          (layer combine -> new h)
template <int MODE>
__global__ void gemm_tanh_kernel(const float* __restrict__ in, const float* __restrict__ W,
                                 const float* __restrict__ base, float* __restrict__ out) {
    __shared__ float row[HIDDEN];
    int n = blockIdx.x;
    int j = threadIdx.x;
    row[j] = in[(size_t)n * HIDDEN + j];
    __syncthreads();
    float s = 0.f;
#pragma unroll 8
    for (int k = 0; k < HIDDEN; ++k) s += row[k] * W[k * HIDDEN + j];
    float t = tanhf(s);
    size_t o = (size_t)n * HIDDEN + j;
    if (MODE == 0)
        out[o] = base[o] + t;
    else if (MODE == 1)
        out[o] += t;
    else
        out[o] = t;
}

// ---- out[j] = sum_n h[n][j] ----
__global__ void reduce_kernel(const float* __restrict__ h, float* __restrict__ out) {
    int j = threadIdx.x;
    float s = 0.f;
    for (int n = blockIdx.x; n < N_NODES; n += gridDim.x)
        s += h[(size_t)n * HIDDEN + j];
    atomicAdd(&out[j], s);
}

extern "C" void kernel_launch(void* const* d_in, const int* in_sizes, int n_in,
                              void* d_out, int out_size, void* d_ws, size_t ws_size,
                              hipStream_t stream) {
    const int* ei = (const int*)d_in[0];
    const float* Win = (const float*)d_in[1];
    const float* Wbr = (const float*)d_in[2];
    const float* Wcb = (const float*)d_in[3];
    float* out = (float*)d_out;

    float* ws = (float*)d_ws;
    float* x = ws;                                    // N_NODES * 4
    float* h = ws + (size_t)N_NODES * N_REL;          // N_NODES * 128
    float* comb = h + (size_t)N_NODES * HIDDEN;       // N_NODES * 128
    float* agg = comb + (size_t)N_NODES * HIDDEN;     // N_NODES * 128

    // x = 0; degree histogram; h = tanh(x @ W_in)
    hipMemsetAsync(x, 0, (size_t)N_NODES * N_REL * sizeof(float), stream);
    dim3 dg((N_EDGES + 255) / 256, N_REL);
    deg_kernel<<<dg, 256, 0, stream>>>(ei, x);
    hinit_kernel<<<(N_NODES * HIDDEN + 255) / 256, 256, 0, stream>>>(x, Win, h);

    for (int l = 0; l < N_LAYERS; ++l) {
        for (int r = 0; r < N_REL; ++r) {
            hipMemsetAsync(agg, 0, (size_t)N_NODES * HIDDEN * sizeof(float), stream);
            const int* src = ei + (size_t)r * 2 * N_EDGES;
            const int* dst = src + N_EDGES;
            scatter_kernel<<<(N_EDGES * 32) / 256, 256, 0, stream>>>(src, dst, h, agg);
            const float* W = Wbr + (size_t)(l * N_REL + r) * HIDDEN * HIDDEN;
            if (r == 0)
                gemm_tanh_kernel<0><<<N_NODES, HIDDEN, 0, stream>>>(agg, W, h, comb);
            else
                gemm_tanh_kernel<1><<<N_NODES, HIDDEN, 0, stream>>>(agg, W, nullptr, comb);
        }
        gemm_tanh_kernel<2><<<N_NODES, HIDDEN, 0, stream>>>(
            comb, Wcb + (size_t)l * HIDDEN * HIDDEN, nullptr, h);
    }

    hipMemsetAsync(out, 0, HIDDEN * sizeof(float), stream);
    reduce_kernel<<<1024, HIDDEN, 0, stream>>>(h, out);
}

// Round 2
// 2133.316 us; speedup vs baseline: 9.1305x; 9.1305x over previous
//
#include <hip/hip_runtime.h>

#define N_NODES 100000
#define N_REL 4
#define N_EDGES 800000
#define HIDDEN 128
#define N_LAYERS 3

#define SCAN_CHUNK 1024
#define N_SCAN_BLOCKS ((N_NODES + SCAN_CHUNK - 1) / SCAN_CHUNK)  // 98

// ---- per-relation in-degree histogram (int) ----
__global__ void count_kernel(const int* __restrict__ ei, int* __restrict__ cnt) {
    int e = blockIdx.x * blockDim.x + threadIdx.x;
    int r = blockIdx.y;
    if (e >= N_EDGES) return;
    int d = ei[(size_t)r * 2 * N_EDGES + N_EDGES + e];
    atomicAdd(&cnt[(size_t)r * N_NODES + d], 1);
}

// ---- scan phase A: per-block sums of 1024-element chunks ----
__global__ void scanA_kernel(const int* __restrict__ cnt, int* __restrict__ partial) {
    __shared__ int ts[256];
    int r = blockIdx.y, b = blockIdx.x, tid = threadIdx.x;
    int base = b * SCAN_CHUNK + tid * 4;
    int s = 0;
#pragma unroll
    for (int i = 0; i < 4; ++i) {
        int n = base + i;
        if (n < N_NODES) s += cnt[(size_t)r * N_NODES + n];
    }
    ts[tid] = s;
    __syncthreads();
    for (int off = 128; off > 0; off >>= 1) {
        if (tid < off) ts[tid] += ts[tid + off];
        __syncthreads();
    }
    if (tid == 0) partial[r * N_SCAN_BLOCKS + b] = ts[0];
}

// ---- scan phase B: serial exclusive scan of 98 partials per relation ----
__global__ void scanB_kernel(int* __restrict__ partial, int* __restrict__ rowptr) {
    int r = threadIdx.x;
    if (r >= N_REL) return;
    int acc = 0;
    for (int b = 0; b < N_SCAN_BLOCKS; ++b) {
        int v = partial[r * N_SCAN_BLOCKS + b];
        partial[r * N_SCAN_BLOCKS + b] = acc;
        acc += v;
    }
    rowptr[(size_t)r * (N_NODES + 1) + N_NODES] = acc;  // == N_EDGES
}

// ---- scan phase C: block-local exclusive scan + offset -> rowptr ----
__global__ void scanC_kernel(const int* __restrict__ cnt, const int* __restrict__ partial,
                             int* __restrict__ rowptr) {
    __shared__ int sa[256], sb[256];
    int r = blockIdx.y, b = blockIdx.x, tid = threadIdx.x;
    int base = b * SCAN_CHUNK + tid * 4;
    int v[4], s = 0;
#pragma unroll
    for (int i = 0; i < 4; ++i) {
        int n = base + i;
        v[i] = (n < N_NODES) ? cnt[(size_t)r * N_NODES + n] : 0;
        s += v[i];
    }
    sa[tid] = s;
    __syncthreads();
    int* pin = sa;
    int* pout = sb;
    for (int off = 1; off < 256; off <<= 1) {
        pout[tid] = pin[tid] + ((tid >= off) ? pin[tid - off] : 0);
        __syncthreads();
        int* t = pin; pin = pout; pout = t;
    }
    int excl = pin[tid] - s + partial[r * N_SCAN_BLOCKS + b];
#pragma unroll
    for (int i = 0; i < 4; ++i) {
        int n = base + i;
        if (n < N_NODES) rowptr[(size_t)r * (N_NODES + 1) + n] = excl;
        excl += v[i];
    }
}

// ---- counting-sort fill: ssorted[rowptr[dst] + cursor[dst]++] = src ----
__global__ void fill_kernel(const int* __restrict__ ei, const int* __restrict__ rowptr,
                            int* __restrict__ cursor, int* __restrict__ ssorted) {
    int e = blockIdx.x * blockDim.x + threadIdx.x;
    int r = blockIdx.y;
    if (e >= N_EDGES) return;
    int s = ei[(size_t)r * 2 * N_EDGES + e];
    int d = ei[(size_t)r * 2 * N_EDGES + N_EDGES + e];
    int pos = rowptr[(size_t)r * (N_NODES + 1) + d] + atomicAdd(&cursor[(size_t)r * N_NODES + d], 1);
    ssorted[(size_t)r * N_EDGES + pos] = s;
}

// ---- h = tanh(x @ W_in), x[n][r] = (float)cnt[r][n] ----
__global__ void hinit_kernel(const int* __restrict__ cnt, const float* __restrict__ Win,
                             float* __restrict__ h) {
    int t = blockIdx.x * blockDim.x + threadIdx.x;
    if (t >= N_NODES * HIDDEN) return;
    int n = t >> 7, j = t & 127;
    float s = 0.f;
#pragma unroll
    for (int r = 0; r < N_REL; ++r)
        s += (float)cnt[(size_t)r * N_NODES + n] * Win[r * HIDDEN + j];
    h[t] = tanhf(s);
}

// ---- gather: agg[n] = sum over in-edges of h[src]; 32 lanes x float4 per node ----
__global__ void gather_kernel(const int* __restrict__ rowptr, const int* __restrict__ ssorted,
                              const float* __restrict__ h, float* __restrict__ agg) {
    int n = blockIdx.x * 8 + (threadIdx.x >> 5);
    int q = threadIdx.x & 31;
    if (n >= N_NODES) return;
    int beg = rowptr[n], end = rowptr[n + 1];
    float4 acc = {0.f, 0.f, 0.f, 0.f};
    for (int e = beg; e < end; ++e) {
        int s = ssorted[e];
        float4 v = ((const float4*)(h + (size_t)s * HIDDEN))[q];
        acc.x += v.x; acc.y += v.y; acc.z += v.z; acc.w += v.w;
    }
    ((float4*)(agg + (size_t)n * HIDDEN))[q] = acc;
}

// ---- tiled GEMM + tanh: out[n][j] (op)= tanh(sum_k in[n][k] * W[k][j]) ----
// 64 nodes/block, 512 threads, thread tile 4 nodes x 4 cols.
// LDS: rows transposed rT[128][68] (34 KB) + W chunk Wl[32][128] (16 KB) = 50 KB.
#define GN 64
#define RSTRIDE 68
template <int MODE>
__global__ __launch_bounds__(512) void gemm_tanh_kernel(const float* __restrict__ in,
                                                        const float* __restrict__ W,
                                                        const float* __restrict__ base,
                                                        float* __restrict__ out) {
    __shared__ float rT[128 * RSTRIDE];
    __shared__ float Wl[32 * 128];
    int tid = threadIdx.x;
    int n0 = blockIdx.x * GN;

    // stage rows transposed: 64 rows x 128 cols, coalesced read
#pragma unroll
    for (int i = 0; i < 16; ++i) {
        int idx = tid + i * 512;  // 0..8191
        int nl = idx >> 7, j = idx & 127;
        int n = n0 + nl;
        float v = (n < N_NODES) ? in[(size_t)n * HIDDEN + j] : 0.f;
        rT[j * RSTRIDE + nl] = v;
    }

    int nt = tid >> 5;  // 0..15 -> nodes nt*4..nt*4+3
    int ct = tid & 31;  // 0..31 -> cols ct*4..ct*4+3
    float acc[4][4] = {};

    for (int kc = 0; kc < 4; ++kc) {
        __syncthreads();
        // stage W rows kc*32..kc*32+31 (4096 floats)
        const float4* Wv = (const float4*)(W + (size_t)kc * 32 * HIDDEN);
        float4* Wlv = (float4*)Wl;
        Wlv[tid] = Wv[tid];
        Wlv[tid + 512] = Wv[tid + 512];
        __syncthreads();
#pragma unroll 4
        for (int kk = 0; kk < 32; ++kk) {
            float4 rv = *(const float4*)(&rT[(kc * 32 + kk) * RSTRIDE + nt * 4]);
            float4 wv = *(const float4*)(&Wl[kk * HIDDEN + ct * 4]);
            float rr[4] = {rv.x, rv.y, rv.z, rv.w};
            float ww[4] = {wv.x, wv.y, wv.z, wv.w};
#pragma unroll
            for (int a = 0; a < 4; ++a)
#pragma unroll
                for (int c = 0; c < 4; ++c) acc[a][c] += rr[a] * ww[c];
        }
    }

#pragma unroll
    for (int a = 0; a < 4; ++a) {
        int n = n0 + nt * 4 + a;
        if (n >= N_NODES) break;
        float4 t;
        t.x = tanhf(acc[a][0]);
        t.y = tanhf(acc[a][1]);
        t.z = tanhf(acc[a][2]);
        t.w = tanhf(acc[a][3]);
        float4* ov = (float4*)(out + (size_t)n * HIDDEN) + ct;
        if (MODE == 0) {
            float4 bv = *((const float4*)(base + (size_t)n * HIDDEN) + ct);
            t.x += bv.x; t.y += bv.y; t.z += bv.z; t.w += bv.w;
            *ov = t;
        } else if (MODE == 1) {
            float4 bv = *ov;
            t.x += bv.x; t.y += bv.y; t.z += bv.z; t.w += bv.w;
            *ov = t;
        } else {
            *ov = t;
        }
    }
}

// ---- out[j] = sum_n h[n][j] ----
__global__ void reduce_kernel(const float* __restrict__ h, float* __restrict__ out) {
    int j = threadIdx.x;
    float s = 0.f;
    for (int n = blockIdx.x; n < N_NODES; n += gridDim.x)
        s += h[(size_t)n * HIDDEN + j];
    atomicAdd(&out[j], s);
}

extern "C" void kernel_launch(void* const* d_in, const int* in_sizes, int n_in,
                              void* d_out, int out_size, void* d_ws, size_t ws_size,
                              hipStream_t stream) {
    const int* ei = (const int*)d_in[0];
    const float* Win = (const float*)d_in[1];
    const float* Wbr = (const float*)d_in[2];
    const float* Wcb = (const float*)d_in[3];
    float* out = (float*)d_out;

    // workspace layout
    char* p = (char*)d_ws;
    int* cnt = (int*)p;      p += (size_t)N_REL * N_NODES * 4;        // 1.6 MB
    int* rowptr = (int*)p;   p += (size_t)N_REL * (N_NODES + 1) * 4;  // 1.6 MB
    int* cursor = (int*)p;   p += (size_t)N_REL * N_NODES * 4;        // 1.6 MB
    int* ssorted = (int*)p;  p += (size_t)N_REL * N_EDGES * 4;        // 12.8 MB
    int* partial = (int*)p;  p += 4096;
    uintptr_t q = ((uintptr_t)p + 511) & ~(uintptr_t)511;
    float* h = (float*)q;
    float* comb = h + (size_t)N_NODES * HIDDEN;
    float* agg = comb + (size_t)N_NODES * HIDDEN;

    // ---- CSR build ----
    hipMemsetAsync(cnt, 0, (size_t)N_REL * N_NODES * 4, stream);
    dim3 eg((N_EDGES + 255) / 256, N_REL);
    count_kernel<<<eg, 256, 0, stream>>>(ei, cnt);
    dim3 sg(N_SCAN_BLOCKS, N_REL);
    scanA_kernel<<<sg, 256, 0, stream>>>(cnt, partial);
    scanB_kernel<<<1, 64, 0, stream>>>(partial, rowptr);
    scanC_kernel<<<sg, 256, 0, stream>>>(cnt, partial, rowptr);
    hipMemsetAsync(cursor, 0, (size_t)N_REL * N_NODES * 4, stream);
    fill_kernel<<<eg, 256, 0, stream>>>(ei, rowptr, cursor, ssorted);

    // ---- h = tanh(deg @ W_in) ----
    hinit_kernel<<<(N_NODES * HIDDEN + 255) / 256, 256, 0, stream>>>(cnt, Win, h);

    // ---- layers ----
    int ggrid = (N_NODES + GN - 1) / GN;
    for (int l = 0; l < N_LAYERS; ++l) {
        for (int r = 0; r < N_REL; ++r) {
            gather_kernel<<<(N_NODES + 7) / 8, 256, 0, stream>>>(
                rowptr + (size_t)r * (N_NODES + 1), ssorted + (size_t)r * N_EDGES, h, agg);
            const float* W = Wbr + (size_t)(l * N_REL + r) * HIDDEN * HIDDEN;
            if (r == 0)
                gemm_tanh_kernel<0><<<ggrid, 512, 0, stream>>>(agg, W, h, comb);
            else
                gemm_tanh_kernel<1><<<ggrid, 512, 0, stream>>>(agg, W, nullptr, comb);
        }
        gemm_tanh_kernel<2><<<ggrid, 512, 0, stream>>>(
            comb, Wcb + (size_t)l * HIDDEN * HIDDEN, nullptr, h);
    }

    hipMemsetAsync(out, 0, HIDDEN * sizeof(float), stream);
    reduce_kernel<<<1024, HIDDEN, 0, stream>>>(h, out);
}

// Round 5
// 1594.072 us; speedup vs baseline: 12.2192x; 1.3383x over previous
//
#include <hip/hip_runtime.h>

#define N_NODES 100000
#define N_REL 4
#define N_EDGES 800000
#define HIDDEN 128
#define N_LAYERS 3

#define SCAN_CHUNK 1024
#define N_SCAN_BLOCKS ((N_NODES + SCAN_CHUNK - 1) / SCAN_CHUNK)  // 98

typedef __attribute__((ext_vector_type(8))) short short8;
typedef __attribute__((ext_vector_type(4))) float f32x4;

__device__ __forceinline__ unsigned short f2bf(float f) {
    unsigned u = __float_as_uint(f);
    u = (u + 0x7fffu + ((u >> 16) & 1u)) >> 16;
    return (unsigned short)u;
}
__device__ __forceinline__ float bf2f(unsigned short b) {
    return __uint_as_float(((unsigned)b) << 16);
}
// overflow-safe tanh: e = exp(-2|x|) in (0,1]; never inf -> never NaN
__device__ __forceinline__ float ftanh(float x) {
    float e = __expf(-2.0f * fabsf(x));
    float t = __fdividef(1.0f - e, 1.0f + e);
    return copysignf(t, x);
}

// ---- per-relation in-degree histogram (int) ----
__global__ void count_kernel(const int* __restrict__ ei, int* __restrict__ cnt) {
    int e = blockIdx.x * blockDim.x + threadIdx.x;
    int r = blockIdx.y;
    if (e >= N_EDGES) return;
    int d = ei[(size_t)r * 2 * N_EDGES + N_EDGES + e];
    atomicAdd(&cnt[(size_t)r * N_NODES + d], 1);
}

// ---- scan phase A ----
__global__ void scanA_kernel(const int* __restrict__ cnt, int* __restrict__ partial) {
    __shared__ int ts[256];
    int r = blockIdx.y, b = blockIdx.x, tid = threadIdx.x;
    int base = b * SCAN_CHUNK + tid * 4;
    int s = 0;
#pragma unroll
    for (int i = 0; i < 4; ++i) {
        int n = base + i;
        if (n < N_NODES) s += cnt[(size_t)r * N_NODES + n];
    }
    ts[tid] = s;
    __syncthreads();
    for (int off = 128; off > 0; off >>= 1) {
        if (tid < off) ts[tid] += ts[tid + off];
        __syncthreads();
    }
    if (tid == 0) partial[r * N_SCAN_BLOCKS + b] = ts[0];
}

// ---- scan phase B ----
__global__ void scanB_kernel(int* __restrict__ partial, int* __restrict__ rowptr) {
    int r = threadIdx.x;
    if (r >= N_REL) return;
    int acc = 0;
    for (int b = 0; b < N_SCAN_BLOCKS; ++b) {
        int v = partial[r * N_SCAN_BLOCKS + b];
        partial[r * N_SCAN_BLOCKS + b] = acc;
        acc += v;
    }
    rowptr[(size_t)r * (N_NODES + 1) + N_NODES] = acc;
}

// ---- scan phase C ----
__global__ void scanC_kernel(const int* __restrict__ cnt, const int* __restrict__ partial,
                             int* __restrict__ rowptr) {
    __shared__ int sa[256], sb[256];
    int r = blockIdx.y, b = blockIdx.x, tid = threadIdx.x;
    int base = b * SCAN_CHUNK + tid * 4;
    int v[4], s = 0;
#pragma unroll
    for (int i = 0; i < 4; ++i) {
        int n = base + i;
        v[i] = (n < N_NODES) ? cnt[(size_t)r * N_NODES + n] : 0;
        s += v[i];
    }
    sa[tid] = s;
    __syncthreads();
    int* pin = sa;
    int* pout = sb;
    for (int off = 1; off < 256; off <<= 1) {
        pout[tid] = pin[tid] + ((tid >= off) ? pin[tid - off] : 0);
        __syncthreads();
        int* t = pin; pin = pout; pout = t;
    }
    int excl = pin[tid] - s + partial[r * N_SCAN_BLOCKS + b];
#pragma unroll
    for (int i = 0; i < 4; ++i) {
        int n = base + i;
        if (n < N_NODES) rowptr[(size_t)r * (N_NODES + 1) + n] = excl;
        excl += v[i];
    }
}

// ---- counting-sort fill ----
__global__ void fill_kernel(const int* __restrict__ ei, const int* __restrict__ rowptr,
                            int* __restrict__ cursor, int* __restrict__ ssorted) {
    int e = blockIdx.x * blockDim.x + threadIdx.x;
    int r = blockIdx.y;
    if (e >= N_EDGES) return;
    int s = ei[(size_t)r * 2 * N_EDGES + e];
    int d = ei[(size_t)r * 2 * N_EDGES + N_EDGES + e];
    int pos = rowptr[(size_t)r * (N_NODES + 1) + d] + atomicAdd(&cursor[(size_t)r * N_NODES + d], 1);
    ssorted[(size_t)r * N_EDGES + pos] = s;
}

// ---- transpose + split-bf16 all 15 weight matrices: WT[m][j][k] = W[m][k][j] ----
__global__ void prepw_kernel(const float* __restrict__ Wbr, const float* __restrict__ Wcb,
                             unsigned short* __restrict__ WTh, unsigned short* __restrict__ WTl) {
    int t = blockIdx.x * blockDim.x + threadIdx.x;
    if (t >= 15 * HIDDEN * HIDDEN) return;
    int m = t >> 14;
    int j = (t >> 7) & 127;
    int k = t & 127;
    float v = (m < 12) ? Wbr[((size_t)m << 14) + k * HIDDEN + j]
                       : Wcb[((size_t)(m - 12) << 14) + k * HIDDEN + j];
    unsigned short hb = f2bf(v);
    WTh[t] = hb;
    WTl[t] = f2bf(v - bf2f(hb));
}

// ---- h0 = tanh(deg @ W_in), f32 ----
__global__ void hinit_kernel(const int* __restrict__ cnt, const float* __restrict__ Win,
                             float* __restrict__ h) {
    int t = blockIdx.x * blockDim.x + threadIdx.x;
    if (t >= N_NODES * 16) return;
    int n = t >> 4, jq = (t & 15) * 8;
    float c0 = (float)cnt[n];
    float c1 = (float)cnt[N_NODES + n];
    float c2 = (float)cnt[2 * N_NODES + n];
    float c3 = (float)cnt[3 * N_NODES + n];
    float o[8];
#pragma unroll
    for (int i = 0; i < 8; ++i) {
        int j = jq + i;
        float s = c0 * Win[j] + c1 * Win[HIDDEN + j] + c2 * Win[2 * HIDDEN + j] +
                  c3 * Win[3 * HIDDEN + j];
        o[i] = ftanh(s);
    }
    float* dst = h + (size_t)n * HIDDEN + jq;
    *(float4*)dst = float4{o[0], o[1], o[2], o[3]};
    *(float4*)(dst + 4) = float4{o[4], o[5], o[6], o[7]};
}

// ---- fused layer: 4x (gather + tanh(agg@Wb)) + tanh(comb@Wc), 64 nodes/block ----
// split-bf16 GEMM: X@W ~= Xh@Wh + Xh@Wl + Xl@Wh  (all bf16 MFMA, f32 accumulate)
__global__ __launch_bounds__(256) void layer_kernel(
    const int* __restrict__ rowptr,                 // [4][N+1]
    const int* __restrict__ ssorted,                // [4][E]
    const float* __restrict__ hin,                  // [N][128] f32
    float* __restrict__ hout,                       // [N][128] f32
    const unsigned short* __restrict__ WTbh,        // [4][128][128] bf16 hi, [col][k]
    const unsigned short* __restrict__ WTbl,        // [4][128][128] bf16 lo
    const unsigned short* __restrict__ WTch,        // [128][128] bf16 hi
    const unsigned short* __restrict__ WTcl) {      // [128][128] bf16 lo
    __shared__ unsigned short atile_h[64 * HIDDEN];  // swizzled [row][col] bf16, 16 KB
    __shared__ unsigned short atile_l[64 * HIDDEN];  // residual tile, 16 KB
    const int tid = threadIdx.x;
    const int n0 = blockIdx.x * 64;
    const int lane = tid & 63;
    const int lrow = lane & 15;   // A-frag row / B-frag col / D col
    const int lk = lane >> 4;     // k-chunk / D row group
    const int wv = tid >> 6;
    const int wcol = wv * 32;     // this wave's output columns
    const int asw = (lrow & 7) << 4;

    const int gn = tid >> 2;      // gather: local node 0..63
    const int gq = tid & 3;       // gather: col quarter (32 f32 cols)
    const int gnode = n0 + gn;
    const int grsw = (gn & 7) << 4;

    // comb init = h_in at D-fragment positions
    float comb[4][2][4];
#pragma unroll
    for (int rt = 0; rt < 4; ++rt)
#pragma unroll
        for (int ct = 0; ct < 2; ++ct)
#pragma unroll
            for (int j = 0; j < 4; ++j) {
                int node = n0 + rt * 16 + lk * 4 + j;
                int col = wcol + ct * 16 + lrow;
                comb[rt][ct][j] = (node < N_NODES) ? hin[(size_t)node * HIDDEN + col] : 0.f;
            }

    for (int r = 0; r < N_REL; ++r) {
        // ---- gather this relation's agg rows (f32) ----
        float acc[32];
#pragma unroll
        for (int i = 0; i < 32; ++i) acc[i] = 0.f;
        if (gnode < N_NODES) {
            const int* rp = rowptr + (size_t)r * (N_NODES + 1);
            int beg = rp[gnode], end = rp[gnode + 1];
            const int* ss = ssorted + (size_t)r * N_EDGES;
            for (int e = beg; e < end; ++e) {
                int s = ss[e];
                const float4* rowp = (const float4*)(hin + (size_t)s * HIDDEN) + gq * 8;
#pragma unroll
                for (int i = 0; i < 8; ++i) {
                    float4 v = rowp[i];
                    acc[i * 4 + 0] += v.x;
                    acc[i * 4 + 1] += v.y;
                    acc[i * 4 + 2] += v.z;
                    acc[i * 4 + 3] += v.w;
                }
            }
        }
        // split hi/lo into LDS (swizzled)
#pragma unroll
        for (int i = 0; i < 4; ++i) {
            short8 ph, pl;
#pragma unroll
            for (int c = 0; c < 8; ++c) {
                float x = acc[i * 8 + c];
                unsigned short hb = f2bf(x);
                ph[c] = (short)hb;
                pl[c] = (short)f2bf(x - bf2f(hb));
            }
            int byt = gn * 256 + ((gq * 64 + i * 16) ^ grsw);
            *(short8*)((char*)atile_h + byt) = ph;
            *(short8*)((char*)atile_l + byt) = pl;
        }
        __syncthreads();

        // ---- comb += tanh(agg @ Wb[r]) via split MFMA ----
        const unsigned short* Wh = WTbh + ((size_t)r << 14);
        const unsigned short* Wl = WTbl + ((size_t)r << 14);
        f32x4 macc[4][2];
#pragma unroll
        for (int rt = 0; rt < 4; ++rt) {
            macc[rt][0] = f32x4{0.f, 0.f, 0.f, 0.f};
            macc[rt][1] = f32x4{0.f, 0.f, 0.f, 0.f};
        }
#pragma unroll
        for (int kb = 0; kb < 4; ++kb) {
            int wo0 = (wcol + lrow) * HIDDEN + kb * 32 + lk * 8;
            int wo1 = (wcol + 16 + lrow) * HIDDEN + kb * 32 + lk * 8;
            short8 b0h = *(const short8*)(Wh + wo0);
            short8 b1h = *(const short8*)(Wh + wo1);
            short8 b0l = *(const short8*)(Wl + wo0);
            short8 b1l = *(const short8*)(Wl + wo1);
#pragma unroll
            for (int rt = 0; rt < 4; ++rt) {
                int ao = (rt * 16 + lrow) * 256 + ((kb * 64 + lk * 16) ^ asw);
                short8 ah = *(const short8*)((const char*)atile_h + ao);
                short8 al = *(const short8*)((const char*)atile_l + ao);
                macc[rt][0] = __builtin_amdgcn_mfma_f32_16x16x32_bf16(ah, b0h, macc[rt][0], 0, 0, 0);
                macc[rt][0] = __builtin_amdgcn_mfma_f32_16x16x32_bf16(ah, b0l, macc[rt][0], 0, 0, 0);
                macc[rt][0] = __builtin_amdgcn_mfma_f32_16x16x32_bf16(al, b0h, macc[rt][0], 0, 0, 0);
                macc[rt][1] = __builtin_amdgcn_mfma_f32_16x16x32_bf16(ah, b1h, macc[rt][1], 0, 0, 0);
                macc[rt][1] = __builtin_amdgcn_mfma_f32_16x16x32_bf16(ah, b1l, macc[rt][1], 0, 0, 0);
                macc[rt][1] = __builtin_amdgcn_mfma_f32_16x16x32_bf16(al, b1h, macc[rt][1], 0, 0, 0);
            }
        }
#pragma unroll
        for (int rt = 0; rt < 4; ++rt)
#pragma unroll
            for (int ct = 0; ct < 2; ++ct)
#pragma unroll
                for (int j = 0; j < 4; ++j) comb[rt][ct][j] += ftanh(macc[rt][ct][j]);
        __syncthreads();
    }

    // ---- combine: comb -> hi/lo tiles (bf16, swizzled, 2B granular) ----
#pragma unroll
    for (int rt = 0; rt < 4; ++rt)
#pragma unroll
        for (int ct = 0; ct < 2; ++ct)
#pragma unroll
            for (int j = 0; j < 4; ++j) {
                int row = rt * 16 + lk * 4 + j;
                int col = wcol + ct * 16 + lrow;
                int byt = row * 256 + ((col * 2) ^ ((row & 7) << 4));
                float x = comb[rt][ct][j];
                unsigned short hb = f2bf(x);
                *(unsigned short*)((char*)atile_h + byt) = hb;
                *(unsigned short*)((char*)atile_l + byt) = f2bf(x - bf2f(hb));
            }
    __syncthreads();

    // ---- h_out = tanh(comb @ Wc) ----
    f32x4 macc[4][2];
#pragma unroll
    for (int rt = 0; rt < 4; ++rt) {
        macc[rt][0] = f32x4{0.f, 0.f, 0.f, 0.f};
        macc[rt][1] = f32x4{0.f, 0.f, 0.f, 0.f};
    }
#pragma unroll
    for (int kb = 0; kb < 4; ++kb) {
        int wo0 = (wcol + lrow) * HIDDEN + kb * 32 + lk * 8;
        int wo1 = (wcol + 16 + lrow) * HIDDEN + kb * 32 + lk * 8;
        short8 b0h = *(const short8*)(WTch + wo0);
        short8 b1h = *(const short8*)(WTch + wo1);
        short8 b0l = *(const short8*)(WTcl + wo0);
        short8 b1l = *(const short8*)(WTcl + wo1);
#pragma unroll
        for (int rt = 0; rt < 4; ++rt) {
            int ao = (rt * 16 + lrow) * 256 + ((kb * 64 + lk * 16) ^ asw);
            short8 ah = *(const short8*)((const char*)atile_h + ao);
            short8 al = *(const short8*)((const char*)atile_l + ao);
            macc[rt][0] = __builtin_amdgcn_mfma_f32_16x16x32_bf16(ah, b0h, macc[rt][0], 0, 0, 0);
            macc[rt][0] = __builtin_amdgcn_mfma_f32_16x16x32_bf16(ah, b0l, macc[rt][0], 0, 0, 0);
            macc[rt][0] = __builtin_amdgcn_mfma_f32_16x16x32_bf16(al, b0h, macc[rt][0], 0, 0, 0);
            macc[rt][1] = __builtin_amdgcn_mfma_f32_16x16x32_bf16(ah, b1h, macc[rt][1], 0, 0, 0);
            macc[rt][1] = __builtin_amdgcn_mfma_f32_16x16x32_bf16(ah, b1l, macc[rt][1], 0, 0, 0);
            macc[rt][1] = __builtin_amdgcn_mfma_f32_16x16x32_bf16(al, b1h, macc[rt][1], 0, 0, 0);
        }
    }
#pragma unroll
    for (int rt = 0; rt < 4; ++rt)
#pragma unroll
        for (int ct = 0; ct < 2; ++ct)
#pragma unroll
            for (int j = 0; j < 4; ++j) {
                int node = n0 + rt * 16 + lk * 4 + j;
                if (node < N_NODES)
                    hout[(size_t)node * HIDDEN + wcol + ct * 16 + lrow] = ftanh(macc[rt][ct][j]);
            }
}

// ---- out[j] = sum_n h[n][j] (f32) ----
__global__ void reduce_kernel(const float* __restrict__ h, float* __restrict__ out) {
    int j = threadIdx.x;
    float s = 0.f;
    for (int n = blockIdx.x; n < N_NODES; n += gridDim.x)
        s += h[(size_t)n * HIDDEN + j];
    atomicAdd(&out[j], s);
}

extern "C" void kernel_launch(void* const* d_in, const int* in_sizes, int n_in,
                              void* d_out, int out_size, void* d_ws, size_t ws_size,
                              hipStream_t stream) {
    const int* ei = (const int*)d_in[0];
    const float* Win = (const float*)d_in[1];
    const float* Wbr = (const float*)d_in[2];
    const float* Wcb = (const float*)d_in[3];
    float* out = (float*)d_out;

    char* p = (char*)d_ws;
    auto alloc = [&](size_t bytes) {
        char* q = p;
        p += (bytes + 511) & ~(size_t)511;
        return q;
    };
    int* cnt = (int*)alloc((size_t)N_REL * N_NODES * 4);
    int* rowptr = (int*)alloc((size_t)N_REL * (N_NODES + 1) * 4);
    int* cursor = (int*)alloc((size_t)N_REL * N_NODES * 4);
    int* ssorted = (int*)alloc((size_t)N_REL * N_EDGES * 4);
    int* partial = (int*)alloc(4096);
    unsigned short* WTh = (unsigned short*)alloc((size_t)15 * HIDDEN * HIDDEN * 2);
    unsigned short* WTl = (unsigned short*)alloc((size_t)15 * HIDDEN * HIDDEN * 2);
    float* h0 = (float*)alloc((size_t)N_NODES * HIDDEN * 4);
    float* h1 = (float*)alloc((size_t)N_NODES * HIDDEN * 4);

    // ---- CSR build ----
    hipMemsetAsync(cnt, 0, (size_t)N_REL * N_NODES * 4, stream);
    dim3 eg((N_EDGES + 255) / 256, N_REL);
    count_kernel<<<eg, 256, 0, stream>>>(ei, cnt);
    dim3 sg(N_SCAN_BLOCKS, N_REL);
    scanA_kernel<<<sg, 256, 0, stream>>>(cnt, partial);
    scanB_kernel<<<1, 64, 0, stream>>>(partial, rowptr);
    scanC_kernel<<<sg, 256, 0, stream>>>(cnt, partial, rowptr);
    hipMemsetAsync(cursor, 0, (size_t)N_REL * N_NODES * 4, stream);
    fill_kernel<<<eg, 256, 0, stream>>>(ei, rowptr, cursor, ssorted);

    // ---- weights + h0 ----
    prepw_kernel<<<(15 * HIDDEN * HIDDEN + 255) / 256, 256, 0, stream>>>(Wbr, Wcb, WTh, WTl);
    hinit_kernel<<<(N_NODES * 16 + 255) / 256, 256, 0, stream>>>(cnt, Win, h0);

    // ---- fused layers (ping-pong h) ----
    int lgrid = (N_NODES + 63) / 64;
    float* hio[2] = {h0, h1};
    for (int l = 0; l < N_LAYERS; ++l) {
        float* hin = hio[l & 1];
        float* hout = hio[(l & 1) ^ 1];
        layer_kernel<<<lgrid, 256, 0, stream>>>(
            rowptr, ssorted, hin, hout,
            WTh + (size_t)(l * 4) * HIDDEN * HIDDEN, WTl + (size_t)(l * 4) * HIDDEN * HIDDEN,
            WTh + (size_t)(12 + l) * HIDDEN * HIDDEN, WTl + (size_t)(12 + l) * HIDDEN * HIDDEN);
    }
    float* hfin = hio[N_LAYERS & 1];

    hipMemsetAsync(out, 0, HIDDEN * sizeof(float), stream);
    reduce_kernel<<<1024, HIDDEN, 0, stream>>>(hfin, out);
}

// Round 6
// 1263.882 us; speedup vs baseline: 15.4115x; 1.2613x over previous
//
#include <hip/hip_runtime.h>

#define N_NODES 100000
#define N_REL 4
#define N_EDGES 800000
#define HIDDEN 128
#define N_LAYERS 3

#define SCAN_CHUNK 1024
#define N_SCAN_BLOCKS ((N_NODES + SCAN_CHUNK - 1) / SCAN_CHUNK)  // 98

typedef __attribute__((ext_vector_type(8))) short short8;
typedef __attribute__((ext_vector_type(4))) float f32x4;

__device__ __forceinline__ unsigned short f2bf(float f) {
    unsigned u = __float_as_uint(f);
    u = (u + 0x7fffu + ((u >> 16) & 1u)) >> 16;
    return (unsigned short)u;
}
__device__ __forceinline__ float bf2f(unsigned short b) {
    return __uint_as_float(((unsigned)b) << 16);
}
// overflow-safe tanh: e = exp(-2|x|) in (0,1]; never inf -> never NaN
__device__ __forceinline__ float ftanh(float x) {
    float e = __expf(-2.0f * fabsf(x));
    float t = __fdividef(1.0f - e, 1.0f + e);
    return copysignf(t, x);
}

// ---- per-relation in-degree histogram (int) ----
__global__ void count_kernel(const int* __restrict__ ei, int* __restrict__ cnt) {
    int e = blockIdx.x * blockDim.x + threadIdx.x;
    int r = blockIdx.y;
    if (e >= N_EDGES) return;
    int d = ei[(size_t)r * 2 * N_EDGES + N_EDGES + e];
    atomicAdd(&cnt[(size_t)r * N_NODES + d], 1);
}

// ---- scan phase A ----
__global__ void scanA_kernel(const int* __restrict__ cnt, int* __restrict__ partial) {
    __shared__ int ts[256];
    int r = blockIdx.y, b = blockIdx.x, tid = threadIdx.x;
    int base = b * SCAN_CHUNK + tid * 4;
    int s = 0;
#pragma unroll
    for (int i = 0; i < 4; ++i) {
        int n = base + i;
        if (n < N_NODES) s += cnt[(size_t)r * N_NODES + n];
    }
    ts[tid] = s;
    __syncthreads();
    for (int off = 128; off > 0; off >>= 1) {
        if (tid < off) ts[tid] += ts[tid + off];
        __syncthreads();
    }
    if (tid == 0) partial[r * N_SCAN_BLOCKS + b] = ts[0];
}

// ---- scan phase B ----
__global__ void scanB_kernel(int* __restrict__ partial, int* __restrict__ rowptr) {
    int r = threadIdx.x;
    if (r >= N_REL) return;
    int acc = 0;
    for (int b = 0; b < N_SCAN_BLOCKS; ++b) {
        int v = partial[r * N_SCAN_BLOCKS + b];
        partial[r * N_SCAN_BLOCKS + b] = acc;
        acc += v;
    }
    rowptr[(size_t)r * (N_NODES + 1) + N_NODES] = acc;
}

// ---- scan phase C ----
__global__ void scanC_kernel(const int* __restrict__ cnt, const int* __restrict__ partial,
                             int* __restrict__ rowptr) {
    __shared__ int sa[256], sb[256];
    int r = blockIdx.y, b = blockIdx.x, tid = threadIdx.x;
    int base = b * SCAN_CHUNK + tid * 4;
    int v[4], s = 0;
#pragma unroll
    for (int i = 0; i < 4; ++i) {
        int n = base + i;
        v[i] = (n < N_NODES) ? cnt[(size_t)r * N_NODES + n] : 0;
        s += v[i];
    }
    sa[tid] = s;
    __syncthreads();
    int* pin = sa;
    int* pout = sb;
    for (int off = 1; off < 256; off <<= 1) {
        pout[tid] = pin[tid] + ((tid >= off) ? pin[tid - off] : 0);
        __syncthreads();
        int* t = pin; pin = pout; pout = t;
    }
    int excl = pin[tid] - s + partial[r * N_SCAN_BLOCKS + b];
#pragma unroll
    for (int i = 0; i < 4; ++i) {
        int n = base + i;
        if (n < N_NODES) rowptr[(size_t)r * (N_NODES + 1) + n] = excl;
        excl += v[i];
    }
}

// ---- counting-sort fill ----
__global__ void fill_kernel(const int* __restrict__ ei, const int* __restrict__ rowptr,
                            int* __restrict__ cursor, int* __restrict__ ssorted) {
    int e = blockIdx.x * blockDim.x + threadIdx.x;
    int r = blockIdx.y;
    if (e >= N_EDGES) return;
    int s = ei[(size_t)r * 2 * N_EDGES + e];
    int d = ei[(size_t)r * 2 * N_EDGES + N_EDGES + e];
    int pos = rowptr[(size_t)r * (N_NODES + 1) + d] + atomicAdd(&cursor[(size_t)r * N_NODES + d], 1);
    ssorted[(size_t)r * N_EDGES + pos] = s;
}

// ---- transpose + split-bf16 all 15 weight matrices: WT[m][j][k] = W[m][k][j] ----
__global__ void prepw_kernel(const float* __restrict__ Wbr, const float* __restrict__ Wcb,
                             unsigned short* __restrict__ WTh, unsigned short* __restrict__ WTl) {
    int t = blockIdx.x * blockDim.x + threadIdx.x;
    if (t >= 15 * HIDDEN * HIDDEN) return;
    int m = t >> 14;
    int j = (t >> 7) & 127;
    int k = t & 127;
    float v = (m < 12) ? Wbr[((size_t)m << 14) + k * HIDDEN + j]
                       : Wcb[((size_t)(m - 12) << 14) + k * HIDDEN + j];
    unsigned short hb = f2bf(v);
    WTh[t] = hb;
    WTl[t] = f2bf(v - bf2f(hb));
}

// ---- h0 = tanh(deg @ W_in): f32 + bf16 shadow ----
__global__ void hinit_kernel(const int* __restrict__ cnt, const float* __restrict__ Win,
                             float* __restrict__ h, unsigned short* __restrict__ hb) {
    int t = blockIdx.x * blockDim.x + threadIdx.x;
    if (t >= N_NODES * 16) return;
    int n = t >> 4, jq = (t & 15) * 8;
    float c0 = (float)cnt[n];
    float c1 = (float)cnt[N_NODES + n];
    float c2 = (float)cnt[2 * N_NODES + n];
    float c3 = (float)cnt[3 * N_NODES + n];
    float o[8];
    short8 ob;
#pragma unroll
    for (int i = 0; i < 8; ++i) {
        int j = jq + i;
        float s = c0 * Win[j] + c1 * Win[HIDDEN + j] + c2 * Win[2 * HIDDEN + j] +
                  c3 * Win[3 * HIDDEN + j];
        o[i] = ftanh(s);
        ob[i] = (short)f2bf(o[i]);
    }
    float* dst = h + (size_t)n * HIDDEN + jq;
    *(float4*)dst = float4{o[0], o[1], o[2], o[3]};
    *(float4*)(dst + 4) = float4{o[4], o[5], o[6], o[7]};
    *(short8*)(hb + (size_t)n * HIDDEN + jq) = ob;
}

// ---- fused layer: 4x (gather + tanh(agg@Wb)) + tanh(comb@Wc), 64 nodes/block ----
// gather reads bf16 shadow of h (half traffic); accumulate f32.
// split-bf16 GEMM: X@W ~= Xh@Wh + Xh@Wl + Xl@Wh  (all bf16 MFMA, f32 accumulate)
__global__ __launch_bounds__(256) void layer_kernel(
    const int* __restrict__ rowptr,                 // [4][N+1]
    const int* __restrict__ ssorted,                // [4][E]
    const float* __restrict__ hin,                  // [N][128] f32 (comb-identity path)
    const unsigned short* __restrict__ hinb,        // [N][128] bf16 (gather path)
    float* __restrict__ hout,                       // [N][128] f32
    unsigned short* __restrict__ houtb,             // [N][128] bf16
    const unsigned short* __restrict__ WTbh,        // [4][128][128] bf16 hi, [col][k]
    const unsigned short* __restrict__ WTbl,        // [4][128][128] bf16 lo
    const unsigned short* __restrict__ WTch,        // [128][128] bf16 hi
    const unsigned short* __restrict__ WTcl) {      // [128][128] bf16 lo
    __shared__ unsigned short atile_h[64 * HIDDEN];  // swizzled [row][col] bf16, 16 KB
    __shared__ unsigned short atile_l[64 * HIDDEN];  // residual tile, 16 KB
    const int tid = threadIdx.x;
    const int n0 = blockIdx.x * 64;
    const int lane = tid & 63;
    const int lrow = lane & 15;   // A-frag row / B-frag col / D col
    const int lk = lane >> 4;     // k-chunk / D row group
    const int wv = tid >> 6;
    const int wcol = wv * 32;     // this wave's output columns
    const int asw = (lrow & 7) << 4;

    const int gn = tid >> 2;      // gather: local node 0..63
    const int gq = tid & 3;       // gather: col quarter (32 cols)
    const int gnode = n0 + gn;
    const int grsw = (gn & 7) << 4;

    // comb init = h_in (f32) at D-fragment positions
    float comb[4][2][4];
#pragma unroll
    for (int rt = 0; rt < 4; ++rt)
#pragma unroll
        for (int ct = 0; ct < 2; ++ct)
#pragma unroll
            for (int j = 0; j < 4; ++j) {
                int node = n0 + rt * 16 + lk * 4 + j;
                int col = wcol + ct * 16 + lrow;
                comb[rt][ct][j] = (node < N_NODES) ? hin[(size_t)node * HIDDEN + col] : 0.f;
            }

    for (int r = 0; r < N_REL; ++r) {
        // ---- gather this relation's agg rows (bf16 -> f32 acc) ----
        float acc[32];
#pragma unroll
        for (int i = 0; i < 32; ++i) acc[i] = 0.f;
        if (gnode < N_NODES) {
            const int* rp = rowptr + (size_t)r * (N_NODES + 1);
            int beg = rp[gnode], end = rp[gnode + 1];
            const int* ss = ssorted + (size_t)r * N_EDGES;
            for (int e = beg; e < end; ++e) {
                int s = ss[e];
                const uint4* rowp = (const uint4*)(hinb + (size_t)s * HIDDEN) + gq * 4;
#pragma unroll
                for (int i = 0; i < 4; ++i) {
                    uint4 v = rowp[i];
                    unsigned uu[4] = {v.x, v.y, v.z, v.w};
#pragma unroll
                    for (int c = 0; c < 4; ++c) {
                        acc[i * 8 + c * 2] += __uint_as_float(uu[c] << 16);
                        acc[i * 8 + c * 2 + 1] += __uint_as_float(uu[c] & 0xffff0000u);
                    }
                }
            }
        }
        // split hi/lo into LDS (swizzled)
#pragma unroll
        for (int i = 0; i < 4; ++i) {
            short8 ph, pl;
#pragma unroll
            for (int c = 0; c < 8; ++c) {
                float x = acc[i * 8 + c];
                unsigned short hb = f2bf(x);
                ph[c] = (short)hb;
                pl[c] = (short)f2bf(x - bf2f(hb));
            }
            int byt = gn * 256 + ((gq * 64 + i * 16) ^ grsw);
            *(short8*)((char*)atile_h + byt) = ph;
            *(short8*)((char*)atile_l + byt) = pl;
        }
        __syncthreads();

        // ---- comb += tanh(agg @ Wb[r]) via split MFMA ----
        const unsigned short* Wh = WTbh + ((size_t)r << 14);
        const unsigned short* Wl = WTbl + ((size_t)r << 14);
        f32x4 macc[4][2];
#pragma unroll
        for (int rt = 0; rt < 4; ++rt) {
            macc[rt][0] = f32x4{0.f, 0.f, 0.f, 0.f};
            macc[rt][1] = f32x4{0.f, 0.f, 0.f, 0.f};
        }
#pragma unroll
        for (int kb = 0; kb < 4; ++kb) {
            int wo0 = (wcol + lrow) * HIDDEN + kb * 32 + lk * 8;
            int wo1 = (wcol + 16 + lrow) * HIDDEN + kb * 32 + lk * 8;
            short8 b0h = *(const short8*)(Wh + wo0);
            short8 b1h = *(const short8*)(Wh + wo1);
            short8 b0l = *(const short8*)(Wl + wo0);
            short8 b1l = *(const short8*)(Wl + wo1);
#pragma unroll
            for (int rt = 0; rt < 4; ++rt) {
                int ao = (rt * 16 + lrow) * 256 + ((kb * 64 + lk * 16) ^ asw);
                short8 ah = *(const short8*)((const char*)atile_h + ao);
                short8 al = *(const short8*)((const char*)atile_l + ao);
                macc[rt][0] = __builtin_amdgcn_mfma_f32_16x16x32_bf16(ah, b0h, macc[rt][0], 0, 0, 0);
                macc[rt][0] = __builtin_amdgcn_mfma_f32_16x16x32_bf16(ah, b0l, macc[rt][0], 0, 0, 0);
                macc[rt][0] = __builtin_amdgcn_mfma_f32_16x16x32_bf16(al, b0h, macc[rt][0], 0, 0, 0);
                macc[rt][1] = __builtin_amdgcn_mfma_f32_16x16x32_bf16(ah, b1h, macc[rt][1], 0, 0, 0);
                macc[rt][1] = __builtin_amdgcn_mfma_f32_16x16x32_bf16(ah, b1l, macc[rt][1], 0, 0, 0);
                macc[rt][1] = __builtin_amdgcn_mfma_f32_16x16x32_bf16(al, b1h, macc[rt][1], 0, 0, 0);
            }
        }
#pragma unroll
        for (int rt = 0; rt < 4; ++rt)
#pragma unroll
            for (int ct = 0; ct < 2; ++ct)
#pragma unroll
                for (int j = 0; j < 4; ++j) comb[rt][ct][j] += ftanh(macc[rt][ct][j]);
        __syncthreads();
    }

    // ---- combine: comb -> hi/lo tiles (bf16, swizzled, 2B granular) ----
#pragma unroll
    for (int rt = 0; rt < 4; ++rt)
#pragma unroll
        for (int ct = 0; ct < 2; ++ct)
#pragma unroll
            for (int j = 0; j < 4; ++j) {
                int row = rt * 16 + lk * 4 + j;
                int col = wcol + ct * 16 + lrow;
                int byt = row * 256 + ((col * 2) ^ ((row & 7) << 4));
                float x = comb[rt][ct][j];
                unsigned short hb = f2bf(x);
                *(unsigned short*)((char*)atile_h + byt) = hb;
                *(unsigned short*)((char*)atile_l + byt) = f2bf(x - bf2f(hb));
            }
    __syncthreads();

    // ---- h_out = tanh(comb @ Wc), write f32 + bf16 shadow ----
    f32x4 macc[4][2];
#pragma unroll
    for (int rt = 0; rt < 4; ++rt) {
        macc[rt][0] = f32x4{0.f, 0.f, 0.f, 0.f};
        macc[rt][1] = f32x4{0.f, 0.f, 0.f, 0.f};
    }
#pragma unroll
    for (int kb = 0; kb < 4; ++kb) {
        int wo0 = (wcol + lrow) * HIDDEN + kb * 32 + lk * 8;
        int wo1 = (wcol + 16 + lrow) * HIDDEN + kb * 32 + lk * 8;
        short8 b0h = *(const short8*)(WTch + wo0);
        short8 b1h = *(const short8*)(WTch + wo1);
        short8 b0l = *(const short8*)(WTcl + wo0);
        short8 b1l = *(const short8*)(WTcl + wo1);
#pragma unroll
        for (int rt = 0; rt < 4; ++rt) {
            int ao = (rt * 16 + lrow) * 256 + ((kb * 64 + lk * 16) ^ asw);
            short8 ah = *(const short8*)((const char*)atile_h + ao);
            short8 al = *(const short8*)((const char*)atile_l + ao);
            macc[rt][0] = __builtin_amdgcn_mfma_f32_16x16x32_bf16(ah, b0h, macc[rt][0], 0, 0, 0);
            macc[rt][0] = __builtin_amdgcn_mfma_f32_16x16x32_bf16(ah, b0l, macc[rt][0], 0, 0, 0);
            macc[rt][0] = __builtin_amdgcn_mfma_f32_16x16x32_bf16(al, b0h, macc[rt][0], 0, 0, 0);
            macc[rt][1] = __builtin_amdgcn_mfma_f32_16x16x32_bf16(ah, b1h, macc[rt][1], 0, 0, 0);
            macc[rt][1] = __builtin_amdgcn_mfma_f32_16x16x32_bf16(ah, b1l, macc[rt][1], 0, 0, 0);
            macc[rt][1] = __builtin_amdgcn_mfma_f32_16x16x32_bf16(al, b1h, macc[rt][1], 0, 0, 0);
        }
    }
#pragma unroll
    for (int rt = 0; rt < 4; ++rt)
#pragma unroll
        for (int ct = 0; ct < 2; ++ct)
#pragma unroll
            for (int j = 0; j < 4; ++j) {
                int node = n0 + rt * 16 + lk * 4 + j;
                if (node < N_NODES) {
                    float t = ftanh(macc[rt][ct][j]);
                    size_t o = (size_t)node * HIDDEN + wcol + ct * 16 + lrow;
                    hout[o] = t;
                    houtb[o] = f2bf(t);
                }
            }
}

// ---- out[j] = sum_n h[n][j] (f32) ----
__global__ void reduce_kernel(const float* __restrict__ h, float* __restrict__ out) {
    int j = threadIdx.x;
    float s = 0.f;
    for (int n = blockIdx.x; n < N_NODES; n += gridDim.x)
        s += h[(size_t)n * HIDDEN + j];
    atomicAdd(&out[j], s);
}

extern "C" void kernel_launch(void* const* d_in, const int* in_sizes, int n_in,
                              void* d_out, int out_size, void* d_ws, size_t ws_size,
                              hipStream_t stream) {
    const int* ei = (const int*)d_in[0];
    const float* Win = (const float*)d_in[1];
    const float* Wbr = (const float*)d_in[2];
    const float* Wcb = (const float*)d_in[3];
    float* out = (float*)d_out;

    char* p = (char*)d_ws;
    auto alloc = [&](size_t bytes) {
        char* q = p;
        p += (bytes + 511) & ~(size_t)511;
        return q;
    };
    int* cnt = (int*)alloc((size_t)N_REL * N_NODES * 4);
    int* rowptr = (int*)alloc((size_t)N_REL * (N_NODES + 1) * 4);
    int* cursor = (int*)alloc((size_t)N_REL * N_NODES * 4);
    int* ssorted = (int*)alloc((size_t)N_REL * N_EDGES * 4);
    int* partial = (int*)alloc(4096);
    unsigned short* WTh = (unsigned short*)alloc((size_t)15 * HIDDEN * HIDDEN * 2);
    unsigned short* WTl = (unsigned short*)alloc((size_t)15 * HIDDEN * HIDDEN * 2);
    float* h0 = (float*)alloc((size_t)N_NODES * HIDDEN * 4);
    float* h1 = (float*)alloc((size_t)N_NODES * HIDDEN * 4);
    unsigned short* hb0 = (unsigned short*)alloc((size_t)N_NODES * HIDDEN * 2);
    unsigned short* hb1 = (unsigned short*)alloc((size_t)N_NODES * HIDDEN * 2);

    // ---- CSR build ----
    hipMemsetAsync(cnt, 0, (size_t)N_REL * N_NODES * 4, stream);
    dim3 eg((N_EDGES + 255) / 256, N_REL);
    count_kernel<<<eg, 256, 0, stream>>>(ei, cnt);
    dim3 sg(N_SCAN_BLOCKS, N_REL);
    scanA_kernel<<<sg, 256, 0, stream>>>(cnt, partial);
    scanB_kernel<<<1, 64, 0, stream>>>(partial, rowptr);
    scanC_kernel<<<sg, 256, 0, stream>>>(cnt, partial, rowptr);
    hipMemsetAsync(cursor, 0, (size_t)N_REL * N_NODES * 4, stream);
    fill_kernel<<<eg, 256, 0, stream>>>(ei, rowptr, cursor, ssorted);

    // ---- weights + h0 ----
    prepw_kernel<<<(15 * HIDDEN * HIDDEN + 255) / 256, 256, 0, stream>>>(Wbr, Wcb, WTh, WTl);
    hinit_kernel<<<(N_NODES * 16 + 255) / 256, 256, 0, stream>>>(cnt, Win, h0, hb0);

    // ---- fused layers (ping-pong h) ----
    int lgrid = (N_NODES + 63) / 64;
    float* hio[2] = {h0, h1};
    unsigned short* hbio[2] = {hb0, hb1};
    for (int l = 0; l < N_LAYERS; ++l) {
        int a = l & 1, b = a ^ 1;
        layer_kernel<<<lgrid, 256, 0, stream>>>(
            rowptr, ssorted, hio[a], hbio[a], hio[b], hbio[b],
            WTh + (size_t)(l * 4) * HIDDEN * HIDDEN, WTl + (size_t)(l * 4) * HIDDEN * HIDDEN,
            WTh + (size_t)(12 + l) * HIDDEN * HIDDEN, WTl + (size_t)(12 + l) * HIDDEN * HIDDEN);
    }
    float* hfin = hio[N_LAYERS & 1];

    hipMemsetAsync(out, 0, HIDDEN * sizeof(float), stream);
    reduce_kernel<<<1024, HIDDEN, 0, stream>>>(hfin, out);
}

// Round 7
// 1080.455 us; speedup vs baseline: 18.0279x; 1.1698x over previous
//
#include <hip/hip_runtime.h>

#define N_NODES 100000
#define N_REL 4
#define N_EDGES 800000
#define HIDDEN 128
#define N_LAYERS 3

#define SCAN_CHUNK 1024
#define N_SCAN_BLOCKS ((N_NODES + SCAN_CHUNK - 1) / SCAN_CHUNK)  // 98

typedef __attribute__((ext_vector_type(8))) short short8;
typedef __attribute__((ext_vector_type(4))) float f32x4;

__device__ __forceinline__ unsigned short f2bf(float f) {
    unsigned u = __float_as_uint(f);
    u = (u + 0x7fffu + ((u >> 16) & 1u)) >> 16;
    return (unsigned short)u;
}
__device__ __forceinline__ float bf2f(unsigned short b) {
    return __uint_as_float(((unsigned)b) << 16);
}
// overflow-safe tanh: e = exp(-2|x|) in (0,1]; never inf -> never NaN
__device__ __forceinline__ float ftanh(float x) {
    float e = __expf(-2.0f * fabsf(x));
    float t = __fdividef(1.0f - e, 1.0f + e);
    return copysignf(t, x);
}

// ---- per-relation in-degree histogram (int) ----
__global__ void count_kernel(const int* __restrict__ ei, int* __restrict__ cnt) {
    int e = blockIdx.x * blockDim.x + threadIdx.x;
    int r = blockIdx.y;
    if (e >= N_EDGES) return;
    int d = ei[(size_t)r * 2 * N_EDGES + N_EDGES + e];
    atomicAdd(&cnt[(size_t)r * N_NODES + d], 1);
}

// ---- scan phase A ----
__global__ void scanA_kernel(const int* __restrict__ cnt, int* __restrict__ partial) {
    __shared__ int ts[256];
    int r = blockIdx.y, b = blockIdx.x, tid = threadIdx.x;
    int base = b * SCAN_CHUNK + tid * 4;
    int s = 0;
#pragma unroll
    for (int i = 0; i < 4; ++i) {
        int n = base + i;
        if (n < N_NODES) s += cnt[(size_t)r * N_NODES + n];
    }
    ts[tid] = s;
    __syncthreads();
    for (int off = 128; off > 0; off >>= 1) {
        if (tid < off) ts[tid] += ts[tid + off];
        __syncthreads();
    }
    if (tid == 0) partial[r * N_SCAN_BLOCKS + b] = ts[0];
}

// ---- scan phase B ----
__global__ void scanB_kernel(int* __restrict__ partial, int* __restrict__ rowptr) {
    int r = threadIdx.x;
    if (r >= N_REL) return;
    int acc = 0;
    for (int b = 0; b < N_SCAN_BLOCKS; ++b) {
        int v = partial[r * N_SCAN_BLOCKS + b];
        partial[r * N_SCAN_BLOCKS + b] = acc;
        acc += v;
    }
    rowptr[(size_t)r * (N_NODES + 1) + N_NODES] = acc;
}

// ---- scan phase C ----
__global__ void scanC_kernel(const int* __restrict__ cnt, const int* __restrict__ partial,
                             int* __restrict__ rowptr) {
    __shared__ int sa[256], sb[256];
    int r = blockIdx.y, b = blockIdx.x, tid = threadIdx.x;
    int base = b * SCAN_CHUNK + tid * 4;
    int v[4], s = 0;
#pragma unroll
    for (int i = 0; i < 4; ++i) {
        int n = base + i;
        v[i] = (n < N_NODES) ? cnt[(size_t)r * N_NODES + n] : 0;
        s += v[i];
    }
    sa[tid] = s;
    __syncthreads();
    int* pin = sa;
    int* pout = sb;
    for (int off = 1; off < 256; off <<= 1) {
        pout[tid] = pin[tid] + ((tid >= off) ? pin[tid - off] : 0);
        __syncthreads();
        int* t = pin; pin = pout; pout = t;
    }
    int excl = pin[tid] - s + partial[r * N_SCAN_BLOCKS + b];
#pragma unroll
    for (int i = 0; i < 4; ++i) {
        int n = base + i;
        if (n < N_NODES) rowptr[(size_t)r * (N_NODES + 1) + n] = excl;
        excl += v[i];
    }
}

// ---- counting-sort fill ----
__global__ void fill_kernel(const int* __restrict__ ei, const int* __restrict__ rowptr,
                            int* __restrict__ cursor, int* __restrict__ ssorted) {
    int e = blockIdx.x * blockDim.x + threadIdx.x;
    int r = blockIdx.y;
    if (e >= N_EDGES) return;
    int s = ei[(size_t)r * 2 * N_EDGES + e];
    int d = ei[(size_t)r * 2 * N_EDGES + N_EDGES + e];
    int pos = rowptr[(size_t)r * (N_NODES + 1) + d] + atomicAdd(&cursor[(size_t)r * N_NODES + d], 1);
    ssorted[(size_t)r * N_EDGES + pos] = s;
}

// ---- transpose + split-bf16 all 15 weight matrices: WT[m][j][k] = W[m][k][j] ----
__global__ void prepw_kernel(const float* __restrict__ Wbr, const float* __restrict__ Wcb,
                             unsigned short* __restrict__ WTh, unsigned short* __restrict__ WTl) {
    int t = blockIdx.x * blockDim.x + threadIdx.x;
    if (t >= 15 * HIDDEN * HIDDEN) return;
    int m = t >> 14;
    int j = (t >> 7) & 127;
    int k = t & 127;
    float v = (m < 12) ? Wbr[((size_t)m << 14) + k * HIDDEN + j]
                       : Wcb[((size_t)(m - 12) << 14) + k * HIDDEN + j];
    unsigned short hb = f2bf(v);
    WTh[t] = hb;
    WTl[t] = f2bf(v - bf2f(hb));
}

// ---- h0 = tanh(deg @ W_in), bf16 ----
__global__ void hinit_kernel(const int* __restrict__ cnt, const float* __restrict__ Win,
                             unsigned short* __restrict__ hb) {
    int t = blockIdx.x * blockDim.x + threadIdx.x;
    if (t >= N_NODES * 16) return;
    int n = t >> 4, jq = (t & 15) * 8;
    float c0 = (float)cnt[n];
    float c1 = (float)cnt[N_NODES + n];
    float c2 = (float)cnt[2 * N_NODES + n];
    float c3 = (float)cnt[3 * N_NODES + n];
    short8 ob;
#pragma unroll
    for (int i = 0; i < 8; ++i) {
        int j = jq + i;
        float s = c0 * Win[j] + c1 * Win[HIDDEN + j] + c2 * Win[2 * HIDDEN + j] +
                  c3 * Win[3 * HIDDEN + j];
        ob[i] = (short)f2bf(ftanh(s));
    }
    *(short8*)(hb + (size_t)n * HIDDEN + jq) = ob;
}

// ---- gather: agg[r][n] = sum_{e in CSR row n of rel r} h[src[e]]; bf16 in/out ----
// 16 lanes per node x 16 nodes per 256-thread block; no LDS; 2-edge unroll for MLP.
__global__ __launch_bounds__(256) void gather_kernel(
    const int* __restrict__ rowptr, const int* __restrict__ ssorted,
    const unsigned short* __restrict__ hinb, unsigned short* __restrict__ agg) {
    const int r = blockIdx.y;
    const int node = blockIdx.x * 16 + (threadIdx.x >> 4);
    const int l16 = threadIdx.x & 15;
    if (node >= N_NODES) return;
    const int* rp = rowptr + (size_t)r * (N_NODES + 1);
    int beg = rp[node], end = rp[node + 1];
    const int* ss = ssorted + (size_t)r * N_EDGES;
    float acc[8];
#pragma unroll
    for (int i = 0; i < 8; ++i) acc[i] = 0.f;
    int e = beg;
    for (; e + 1 < end; e += 2) {
        int s0 = ss[e], s1 = ss[e + 1];
        uint4 v0 = *((const uint4*)(hinb + (size_t)s0 * HIDDEN) + l16);
        uint4 v1 = *((const uint4*)(hinb + (size_t)s1 * HIDDEN) + l16);
        unsigned a0[4] = {v0.x, v0.y, v0.z, v0.w};
        unsigned a1[4] = {v1.x, v1.y, v1.z, v1.w};
#pragma unroll
        for (int c = 0; c < 4; ++c) {
            acc[c * 2] += __uint_as_float(a0[c] << 16) + __uint_as_float(a1[c] << 16);
            acc[c * 2 + 1] +=
                __uint_as_float(a0[c] & 0xffff0000u) + __uint_as_float(a1[c] & 0xffff0000u);
        }
    }
    if (e < end) {
        int s0 = ss[e];
        uint4 v0 = *((const uint4*)(hinb + (size_t)s0 * HIDDEN) + l16);
        unsigned a0[4] = {v0.x, v0.y, v0.z, v0.w};
#pragma unroll
        for (int c = 0; c < 4; ++c) {
            acc[c * 2] += __uint_as_float(a0[c] << 16);
            acc[c * 2 + 1] += __uint_as_float(a0[c] & 0xffff0000u);
        }
    }
    short8 pk;
#pragma unroll
    for (int c = 0; c < 8; ++c) pk[c] = (short)f2bf(acc[c]);
    *(short8*)(agg + ((size_t)r * N_NODES + node) * HIDDEN + l16 * 8) = pk;
}

// ---- GEMM: h_out = tanh( (h_in + sum_r tanh(agg_r @ Wb_r)) @ Wc ), 64 nodes/block ----
// branch: A (bf16 agg) exact -> 2 terms Ah@Wh + Ah@Wl
// combine: comb f32 -> hi/lo split -> 3 terms
__global__ __launch_bounds__(256) void gemm_kernel(
    const unsigned short* __restrict__ agg,         // [4][N][128] bf16
    const unsigned short* __restrict__ hinb,        // [N][128] bf16
    unsigned short* __restrict__ houtb,             // [N][128] bf16
    const unsigned short* __restrict__ WTbh,        // [4][128][128] bf16 hi, [col][k]
    const unsigned short* __restrict__ WTbl,        // [4][128][128] bf16 lo
    const unsigned short* __restrict__ WTch,        // [128][128] bf16 hi
    const unsigned short* __restrict__ WTcl) {      // [128][128] bf16 lo
    __shared__ unsigned short atile_h[64 * HIDDEN];  // swizzled [row][col] bf16, 16 KB
    __shared__ unsigned short atile_l[64 * HIDDEN];  // residual tile (combine only), 16 KB
    const int tid = threadIdx.x;
    const int n0 = blockIdx.x * 64;
    const int lane = tid & 63;
    const int lrow = lane & 15;   // A-frag row / B-frag col / D col
    const int lk = lane >> 4;     // k-chunk / D row group
    const int wv = tid >> 6;
    const int wcol = wv * 32;     // this wave's output columns
    const int asw = (lrow & 7) << 4;

    const int gn = tid >> 2;      // staging: local node 0..63
    const int gq = tid & 3;       // staging: col quarter (32 cols = 64 B)
    const int gnode = n0 + gn;
    const int grsw = (gn & 7) << 4;

    // comb init = h_in (bf16) at D-fragment positions
    float comb[4][2][4];
#pragma unroll
    for (int rt = 0; rt < 4; ++rt)
#pragma unroll
        for (int ct = 0; ct < 2; ++ct)
#pragma unroll
            for (int j = 0; j < 4; ++j) {
                int node = n0 + rt * 16 + lk * 4 + j;
                int col = wcol + ct * 16 + lrow;
                comb[rt][ct][j] =
                    (node < N_NODES) ? bf2f(hinb[(size_t)node * HIDDEN + col]) : 0.f;
            }

    for (int r = 0; r < N_REL; ++r) {
        // ---- stage agg[r] tile into swizzled LDS (coalesced) ----
        const unsigned short* aggr = agg + (size_t)r * N_NODES * HIDDEN;
#pragma unroll
        for (int i = 0; i < 4; ++i) {
            uint4 v = (gnode < N_NODES)
                          ? *((const uint4*)(aggr + (size_t)gnode * HIDDEN) + gq * 4 + i)
                          : uint4{0u, 0u, 0u, 0u};
            int byt = gn * 256 + ((gq * 64 + i * 16) ^ grsw);
            *(uint4*)((char*)atile_h + byt) = v;
        }
        __syncthreads();

        // ---- comb += tanh(agg @ Wb[r]) via 2-term split MFMA ----
        const unsigned short* Wh = WTbh + ((size_t)r << 14);
        const unsigned short* Wl = WTbl + ((size_t)r << 14);
        f32x4 macc[4][2];
#pragma unroll
        for (int rt = 0; rt < 4; ++rt) {
            macc[rt][0] = f32x4{0.f, 0.f, 0.f, 0.f};
            macc[rt][1] = f32x4{0.f, 0.f, 0.f, 0.f};
        }
#pragma unroll
        for (int kb = 0; kb < 4; ++kb) {
            int wo0 = (wcol + lrow) * HIDDEN + kb * 32 + lk * 8;
            int wo1 = (wcol + 16 + lrow) * HIDDEN + kb * 32 + lk * 8;
            short8 b0h = *(const short8*)(Wh + wo0);
            short8 b1h = *(const short8*)(Wh + wo1);
            short8 b0l = *(const short8*)(Wl + wo0);
            short8 b1l = *(const short8*)(Wl + wo1);
#pragma unroll
            for (int rt = 0; rt < 4; ++rt) {
                int ao = (rt * 16 + lrow) * 256 + ((kb * 64 + lk * 16) ^ asw);
                short8 ah = *(const short8*)((const char*)atile_h + ao);
                macc[rt][0] = __builtin_amdgcn_mfma_f32_16x16x32_bf16(ah, b0h, macc[rt][0], 0, 0, 0);
                macc[rt][0] = __builtin_amdgcn_mfma_f32_16x16x32_bf16(ah, b0l, macc[rt][0], 0, 0, 0);
                macc[rt][1] = __builtin_amdgcn_mfma_f32_16x16x32_bf16(ah, b1h, macc[rt][1], 0, 0, 0);
                macc[rt][1] = __builtin_amdgcn_mfma_f32_16x16x32_bf16(ah, b1l, macc[rt][1], 0, 0, 0);
            }
        }
#pragma unroll
        for (int rt = 0; rt < 4; ++rt)
#pragma unroll
            for (int ct = 0; ct < 2; ++ct)
#pragma unroll
                for (int j = 0; j < 4; ++j) comb[rt][ct][j] += ftanh(macc[rt][ct][j]);
        __syncthreads();
    }

    // ---- combine: comb -> hi/lo tiles (bf16, swizzled, 2B granular) ----
#pragma unroll
    for (int rt = 0; rt < 4; ++rt)
#pragma unroll
        for (int ct = 0; ct < 2; ++ct)
#pragma unroll
            for (int j = 0; j < 4; ++j) {
                int row = rt * 16 + lk * 4 + j;
                int col = wcol + ct * 16 + lrow;
                int byt = row * 256 + ((col * 2) ^ ((row & 7) << 4));
                float x = comb[rt][ct][j];
                unsigned short hb = f2bf(x);
                *(unsigned short*)((char*)atile_h + byt) = hb;
                *(unsigned short*)((char*)atile_l + byt) = f2bf(x - bf2f(hb));
            }
    __syncthreads();

    // ---- h_out = tanh(comb @ Wc), 3-term split ----
    f32x4 macc[4][2];
#pragma unroll
    for (int rt = 0; rt < 4; ++rt) {
        macc[rt][0] = f32x4{0.f, 0.f, 0.f, 0.f};
        macc[rt][1] = f32x4{0.f, 0.f, 0.f, 0.f};
    }
#pragma unroll
    for (int kb = 0; kb < 4; ++kb) {
        int wo0 = (wcol + lrow) * HIDDEN + kb * 32 + lk * 8;
        int wo1 = (wcol + 16 + lrow) * HIDDEN + kb * 32 + lk * 8;
        short8 b0h = *(const short8*)(WTch + wo0);
        short8 b1h = *(const short8*)(WTch + wo1);
        short8 b0l = *(const short8*)(WTcl + wo0);
        short8 b1l = *(const short8*)(WTcl + wo1);
#pragma unroll
        for (int rt = 0; rt < 4; ++rt) {
            int ao = (rt * 16 + lrow) * 256 + ((kb * 64 + lk * 16) ^ asw);
            short8 ah = *(const short8*)((const char*)atile_h + ao);
            short8 al = *(const short8*)((const char*)atile_l + ao);
            macc[rt][0] = __builtin_amdgcn_mfma_f32_16x16x32_bf16(ah, b0h, macc[rt][0], 0, 0, 0);
            macc[rt][0] = __builtin_amdgcn_mfma_f32_16x16x32_bf16(ah, b0l, macc[rt][0], 0, 0, 0);
            macc[rt][0] = __builtin_amdgcn_mfma_f32_16x16x32_bf16(al, b0h, macc[rt][0], 0, 0, 0);
            macc[rt][1] = __builtin_amdgcn_mfma_f32_16x16x32_bf16(ah, b1h, macc[rt][1], 0, 0, 0);
            macc[rt][1] = __builtin_amdgcn_mfma_f32_16x16x32_bf16(ah, b1l, macc[rt][1], 0, 0, 0);
            macc[rt][1] = __builtin_amdgcn_mfma_f32_16x16x32_bf16(al, b1h, macc[rt][1], 0, 0, 0);
        }
    }
#pragma unroll
    for (int rt = 0; rt < 4; ++rt)
#pragma unroll
        for (int ct = 0; ct < 2; ++ct)
#pragma unroll
            for (int j = 0; j < 4; ++j) {
                int node = n0 + rt * 16 + lk * 4 + j;
                if (node < N_NODES)
                    houtb[(size_t)node * HIDDEN + wcol + ct * 16 + lrow] =
                        f2bf(ftanh(macc[rt][ct][j]));
            }
}

// ---- out[j] = sum_n h[n][j] (bf16 in, f32 out) ----
__global__ void reduce_kernel(const unsigned short* __restrict__ h, float* __restrict__ out) {
    int j = threadIdx.x;
    float s = 0.f;
    for (int n = blockIdx.x; n < N_NODES; n += gridDim.x)
        s += bf2f(h[(size_t)n * HIDDEN + j]);
    atomicAdd(&out[j], s);
}

extern "C" void kernel_launch(void* const* d_in, const int* in_sizes, int n_in,
                              void* d_out, int out_size, void* d_ws, size_t ws_size,
                              hipStream_t stream) {
    const int* ei = (const int*)d_in[0];
    const float* Win = (const float*)d_in[1];
    const float* Wbr = (const float*)d_in[2];
    const float* Wcb = (const float*)d_in[3];
    float* out = (float*)d_out;

    char* p = (char*)d_ws;
    auto alloc = [&](size_t bytes) {
        char* q = p;
        p += (bytes + 511) & ~(size_t)511;
        return q;
    };
    int* cnt = (int*)alloc((size_t)N_REL * N_NODES * 4);
    int* rowptr = (int*)alloc((size_t)N_REL * (N_NODES + 1) * 4);
    int* cursor = (int*)alloc((size_t)N_REL * N_NODES * 4);
    int* ssorted = (int*)alloc((size_t)N_REL * N_EDGES * 4);
    int* partial = (int*)alloc(4096);
    unsigned short* WTh = (unsigned short*)alloc((size_t)15 * HIDDEN * HIDDEN * 2);
    unsigned short* WTl = (unsigned short*)alloc((size_t)15 * HIDDEN * HIDDEN * 2);
    unsigned short* hb0 = (unsigned short*)alloc((size_t)N_NODES * HIDDEN * 2);
    unsigned short* hb1 = (unsigned short*)alloc((size_t)N_NODES * HIDDEN * 2);
    unsigned short* agg = (unsigned short*)alloc((size_t)N_REL * N_NODES * HIDDEN * 2);

    // ---- CSR build ----
    hipMemsetAsync(cnt, 0, (size_t)N_REL * N_NODES * 4, stream);
    dim3 eg((N_EDGES + 255) / 256, N_REL);
    count_kernel<<<eg, 256, 0, stream>>>(ei, cnt);
    dim3 sg(N_SCAN_BLOCKS, N_REL);
    scanA_kernel<<<sg, 256, 0, stream>>>(cnt, partial);
    scanB_kernel<<<1, 64, 0, stream>>>(partial, rowptr);
    scanC_kernel<<<sg, 256, 0, stream>>>(cnt, partial, rowptr);
    hipMemsetAsync(cursor, 0, (size_t)N_REL * N_NODES * 4, stream);
    fill_kernel<<<eg, 256, 0, stream>>>(ei, rowptr, cursor, ssorted);

    // ---- weights + h0 ----
    prepw_kernel<<<(15 * HIDDEN * HIDDEN + 255) / 256, 256, 0, stream>>>(Wbr, Wcb, WTh, WTl);
    hinit_kernel<<<(N_NODES * 16 + 255) / 256, 256, 0, stream>>>(cnt, Win, hb0);

    // ---- layers: gather (per relation) + fused GEMM ----
    dim3 gg((N_NODES + 15) / 16, N_REL);
    int cgrid = (N_NODES + 63) / 64;
    unsigned short* hbio[2] = {hb0, hb1};
    for (int l = 0; l < N_LAYERS; ++l) {
        int a = l & 1, b = a ^ 1;
        gather_kernel<<<gg, 256, 0, stream>>>(rowptr, ssorted, hbio[a], agg);
        gemm_kernel<<<cgrid, 256, 0, stream>>>(
            agg, hbio[a], hbio[b],
            WTh + (size_t)(l * 4) * HIDDEN * HIDDEN, WTl + (size_t)(l * 4) * HIDDEN * HIDDEN,
            WTh + (size_t)(12 + l) * HIDDEN * HIDDEN, WTl + (size_t)(12 + l) * HIDDEN * HIDDEN);
    }
    unsigned short* hfin = hbio[N_LAYERS & 1];

    hipMemsetAsync(out, 0, HIDDEN * sizeof(float), stream);
    reduce_kernel<<<1024, HIDDEN, 0, stream>>>(hfin, out);
}

// Round 8
// 828.294 us; speedup vs baseline: 23.5162x; 1.3044x over previous
//
#include <hip/hip_runtime.h>

#define N_NODES 100000
#define N_REL 4
#define N_EDGES 800000
#define HIDDEN 128
#define N_LAYERS 3

#define NBUCK 196   // ceil(100000/512) buckets of 512 nodes
#define NBB 196     // ceil(800000/4096) edge blocks
#define EPB 4096    // edges per bin block
#define BMAX 8192   // bucket_sort LDS staging capacity (mean 4082, std 64)

typedef __attribute__((ext_vector_type(8))) short short8;
typedef __attribute__((ext_vector_type(4))) float f32x4;

__device__ __forceinline__ unsigned short f2bf(float f) {
    unsigned u = __float_as_uint(f);
    u = (u + 0x7fffu + ((u >> 16) & 1u)) >> 16;
    return (unsigned short)u;
}
__device__ __forceinline__ float bf2f(unsigned short b) {
    return __uint_as_float(((unsigned)b) << 16);
}
// overflow-safe tanh: e = exp(-2|x|) in (0,1]; never inf -> never NaN
__device__ __forceinline__ float ftanh(float x) {
    float e = __expf(-2.0f * fabsf(x));
    float t = __fdividef(1.0f - e, 1.0f + e);
    return copysignf(t, x);
}

// ==================== CSR build: two-level bucketed counting sort ====================

// per-block bucket histogram: bh[r][bucket][block]
__global__ __launch_bounds__(256) void bin_hist(const int* __restrict__ ei, int* __restrict__ bh) {
    __shared__ int hist[NBUCK];
    int r = blockIdx.y, blk = blockIdx.x, tid = threadIdx.x;
    for (int i = tid; i < NBUCK; i += 256) hist[i] = 0;
    __syncthreads();
    const int* dst = ei + (size_t)r * 2 * N_EDGES + N_EDGES;
#pragma unroll
    for (int i = 0; i < EPB / 256; ++i) {
        int e = blk * EPB + i * 256 + tid;
        if (e < N_EDGES) atomicAdd(&hist[dst[e] >> 9], 1);
    }
    __syncthreads();
    for (int i = tid; i < NBUCK; i += 256)
        bh[((size_t)r * NBUCK + i) * NBB + blk] = hist[i];
}

// per-bucket exclusive scan over blocks (in place); bucket totals out
__global__ __launch_bounds__(256) void bin_scan(int* __restrict__ bh, int* __restrict__ btot) {
    __shared__ int sa[256], sb[256];
    int r = blockIdx.y, b = blockIdx.x, tid = threadIdx.x;
    int* row = bh + ((size_t)r * NBUCK + b) * NBB;
    int v = (tid < NBB) ? row[tid] : 0;
    sa[tid] = v;
    __syncthreads();
    int* pin = sa;
    int* pout = sb;
    for (int off = 1; off < 256; off <<= 1) {
        pout[tid] = pin[tid] + ((tid >= off) ? pin[tid - off] : 0);
        __syncthreads();
        int* t = pin; pin = pout; pout = t;
    }
    if (tid < NBB) row[tid] = pin[tid] - v;
    if (tid == NBB - 1) btot[r * NBUCK + b] = pin[tid];
}

// scan bucket totals -> bucket bases (+ sentinel); set rowptr[N]
__global__ void bin_base(const int* __restrict__ btot, int* __restrict__ bbase,
                         int* __restrict__ rowptr) {
    int r = threadIdx.x;
    if (r >= N_REL) return;
    int acc = 0;
    for (int b = 0; b < NBUCK; ++b) {
        bbase[r * (NBUCK + 1) + b] = acc;
        acc += btot[r * NBUCK + b];
    }
    bbase[r * (NBUCK + 1) + NBUCK] = acc;  // == N_EDGES
    rowptr[(size_t)r * (N_NODES + 1) + N_NODES] = N_EDGES;
}

// group each 4096-edge block by bucket in LDS; write bucket-contiguous runs
__global__ __launch_bounds__(256) void bin_scatter(const int* __restrict__ ei,
                                                   const int* __restrict__ bh,
                                                   const int* __restrict__ bbase,
                                                   unsigned* __restrict__ staging) {
    __shared__ int hist[NBUCK];
    __shared__ int runStart[NBUCK + 1];
    __shared__ int runBaseG[NBUCK];
    __shared__ int curs[NBUCK];
    __shared__ unsigned packed[EPB];
    __shared__ int sa[256], sb[256];
    int r = blockIdx.y, blk = blockIdx.x, tid = threadIdx.x;
    const int* src = ei + (size_t)r * 2 * N_EDGES;
    const int* dst = src + N_EDGES;
    int e0 = blk * EPB;
    int ecnt = min(EPB, N_EDGES - e0);
    for (int i = tid; i < NBUCK; i += 256) hist[i] = 0;
    __syncthreads();
#pragma unroll
    for (int i = 0; i < EPB / 256; ++i) {
        int e = e0 + i * 256 + tid;
        if (e < N_EDGES) atomicAdd(&hist[dst[e] >> 9], 1);
    }
    __syncthreads();
    int v = (tid < NBUCK) ? hist[tid] : 0;
    sa[tid] = v;
    __syncthreads();
    int* pin = sa;
    int* pout = sb;
    for (int off = 1; off < 256; off <<= 1) {
        pout[tid] = pin[tid] + ((tid >= off) ? pin[tid - off] : 0);
        __syncthreads();
        int* t = pin; pin = pout; pout = t;
    }
    if (tid < NBUCK) {
        runStart[tid] = pin[tid] - v;
        curs[tid] = 0;
        runBaseG[tid] = bbase[r * (NBUCK + 1) + tid] + bh[((size_t)r * NBUCK + tid) * NBB + blk];
    }
    if (tid == 0) runStart[NBUCK] = ecnt;
    __syncthreads();
#pragma unroll
    for (int i = 0; i < EPB / 256; ++i) {
        int e = e0 + i * 256 + tid;
        if (e < N_EDGES) {
            int d = dst[e];
            int b = d >> 9;
            int lp = runStart[b] + atomicAdd(&curs[b], 1);
            packed[lp] = ((unsigned)(d & 511) << 17) | (unsigned)src[e];
        }
    }
    __syncthreads();
    for (int i = tid; i < ecnt; i += 256) {
        int lo = 0, hi = NBUCK;  // runStart[lo] <= i < runStart[hi]
        while (hi - lo > 1) {
            int mid = (lo + hi) >> 1;
            if (runStart[mid] <= i) lo = mid;
            else hi = mid;
        }
        staging[(size_t)r * N_EDGES + runBaseG[lo] + (i - runStart[lo])] = packed[i];
    }
}

// per-bucket counting sort by exact dst; emits rowptr, cnt(degree), coalesced ssorted
__global__ __launch_bounds__(512) void bucket_sort(const unsigned* __restrict__ staging,
                                                   const int* __restrict__ bbase,
                                                   int* __restrict__ rowptr, int* __restrict__ cnt,
                                                   int* __restrict__ ssorted) {
    __shared__ int c512[512];
    __shared__ int lrp[512];
    __shared__ int curs[512];
    __shared__ int sb2[512];
    __shared__ int outbuf[BMAX];
    int r = blockIdx.y, b = blockIdx.x, tid = threadIdx.x;
    int base = bbase[r * (NBUCK + 1) + b];
    int total = bbase[r * (NBUCK + 1) + b + 1] - base;
    const unsigned* st = staging + (size_t)r * N_EDGES + base;
    c512[tid] = 0;
    __syncthreads();
    for (int i = tid; i < total; i += 512) atomicAdd(&c512[st[i] >> 17], 1);
    __syncthreads();
    int v = c512[tid];
    lrp[tid] = v;
    __syncthreads();
    int* pin = lrp;
    int* pout = sb2;
    for (int off = 1; off < 512; off <<= 1) {
        pout[tid] = pin[tid] + ((tid >= off) ? pin[tid - off] : 0);
        __syncthreads();
        int* t = pin; pin = pout; pout = t;
    }
    int excl = pin[tid] - v;
    __syncthreads();
    lrp[tid] = excl;
    curs[tid] = 0;
    int node = b * 512 + tid;
    if (node < N_NODES) {
        rowptr[(size_t)r * (N_NODES + 1) + node] = base + excl;
        cnt[(size_t)r * N_NODES + node] = v;
    }
    __syncthreads();
    if (total <= BMAX) {
        for (int i = tid; i < total; i += 512) {
            unsigned p = st[i];
            int dl = p >> 17;
            int pos = lrp[dl] + atomicAdd(&curs[dl], 1);
            outbuf[pos] = (int)(p & 0x1FFFFu);
        }
        __syncthreads();
        for (int i = tid; i < total; i += 512)
            ssorted[(size_t)r * N_EDGES + base + i] = outbuf[i];
    } else {  // statistically unreachable fallback
        for (int i = tid; i < total; i += 512) {
            unsigned p = st[i];
            int dl = p >> 17;
            int pos = lrp[dl] + atomicAdd(&curs[dl], 1);
            ssorted[(size_t)r * N_EDGES + base + pos] = (int)(p & 0x1FFFFu);
        }
    }
}

// ==================== dense pipeline (unchanged from R7) ====================

// ---- transpose + split-bf16 all 15 weight matrices: WT[m][j][k] = W[m][k][j] ----
__global__ void prepw_kernel(const float* __restrict__ Wbr, const float* __restrict__ Wcb,
                             unsigned short* __restrict__ WTh, unsigned short* __restrict__ WTl) {
    int t = blockIdx.x * blockDim.x + threadIdx.x;
    if (t >= 15 * HIDDEN * HIDDEN) return;
    int m = t >> 14;
    int j = (t >> 7) & 127;
    int k = t & 127;
    float v = (m < 12) ? Wbr[((size_t)m << 14) + k * HIDDEN + j]
                       : Wcb[((size_t)(m - 12) << 14) + k * HIDDEN + j];
    unsigned short hb = f2bf(v);
    WTh[t] = hb;
    WTl[t] = f2bf(v - bf2f(hb));
}

// ---- h0 = tanh(deg @ W_in), bf16 ----
__global__ void hinit_kernel(const int* __restrict__ cnt, const float* __restrict__ Win,
                             unsigned short* __restrict__ hb) {
    int t = blockIdx.x * blockDim.x + threadIdx.x;
    if (t >= N_NODES * 16) return;
    int n = t >> 4, jq = (t & 15) * 8;
    float c0 = (float)cnt[n];
    float c1 = (float)cnt[N_NODES + n];
    float c2 = (float)cnt[2 * N_NODES + n];
    float c3 = (float)cnt[3 * N_NODES + n];
    short8 ob;
#pragma unroll
    for (int i = 0; i < 8; ++i) {
        int j = jq + i;
        float s = c0 * Win[j] + c1 * Win[HIDDEN + j] + c2 * Win[2 * HIDDEN + j] +
                  c3 * Win[3 * HIDDEN + j];
        ob[i] = (short)f2bf(ftanh(s));
    }
    *(short8*)(hb + (size_t)n * HIDDEN + jq) = ob;
}

// ---- gather: agg[r][n] = sum_{e in CSR row n of rel r} h[src[e]]; bf16 in/out ----
__global__ __launch_bounds__(256) void gather_kernel(
    const int* __restrict__ rowptr, const int* __restrict__ ssorted,
    const unsigned short* __restrict__ hinb, unsigned short* __restrict__ agg) {
    const int r = blockIdx.y;
    const int node = blockIdx.x * 16 + (threadIdx.x >> 4);
    const int l16 = threadIdx.x & 15;
    if (node >= N_NODES) return;
    const int* rp = rowptr + (size_t)r * (N_NODES + 1);
    int beg = rp[node], end = rp[node + 1];
    const int* ss = ssorted + (size_t)r * N_EDGES;
    float acc[8];
#pragma unroll
    for (int i = 0; i < 8; ++i) acc[i] = 0.f;
    int e = beg;
    for (; e + 1 < end; e += 2) {
        int s0 = ss[e], s1 = ss[e + 1];
        uint4 v0 = *((const uint4*)(hinb + (size_t)s0 * HIDDEN) + l16);
        uint4 v1 = *((const uint4*)(hinb + (size_t)s1 * HIDDEN) + l16);
        unsigned a0[4] = {v0.x, v0.y, v0.z, v0.w};
        unsigned a1[4] = {v1.x, v1.y, v1.z, v1.w};
#pragma unroll
        for (int c = 0; c < 4; ++c) {
            acc[c * 2] += __uint_as_float(a0[c] << 16) + __uint_as_float(a1[c] << 16);
            acc[c * 2 + 1] +=
                __uint_as_float(a0[c] & 0xffff0000u) + __uint_as_float(a1[c] & 0xffff0000u);
        }
    }
    if (e < end) {
        int s0 = ss[e];
        uint4 v0 = *((const uint4*)(hinb + (size_t)s0 * HIDDEN) + l16);
        unsigned a0[4] = {v0.x, v0.y, v0.z, v0.w};
#pragma unroll
        for (int c = 0; c < 4; ++c) {
            acc[c * 2] += __uint_as_float(a0[c] << 16);
            acc[c * 2 + 1] += __uint_as_float(a0[c] & 0xffff0000u);
        }
    }
    short8 pk;
#pragma unroll
    for (int c = 0; c < 8; ++c) pk[c] = (short)f2bf(acc[c]);
    *(short8*)(agg + ((size_t)r * N_NODES + node) * HIDDEN + l16 * 8) = pk;
}

// ---- GEMM: h_out = tanh( (h_in + sum_r tanh(agg_r @ Wb_r)) @ Wc ), 64 nodes/block ----
__global__ __launch_bounds__(256) void gemm_kernel(
    const unsigned short* __restrict__ agg,         // [4][N][128] bf16
    const unsigned short* __restrict__ hinb,        // [N][128] bf16
    unsigned short* __restrict__ houtb,             // [N][128] bf16
    const unsigned short* __restrict__ WTbh,        // [4][128][128] bf16 hi, [col][k]
    const unsigned short* __restrict__ WTbl,        // [4][128][128] bf16 lo
    const unsigned short* __restrict__ WTch,        // [128][128] bf16 hi
    const unsigned short* __restrict__ WTcl) {      // [128][128] bf16 lo
    __shared__ unsigned short atile_h[64 * HIDDEN];
    __shared__ unsigned short atile_l[64 * HIDDEN];
    const int tid = threadIdx.x;
    const int n0 = blockIdx.x * 64;
    const int lane = tid & 63;
    const int lrow = lane & 15;
    const int lk = lane >> 4;
    const int wv = tid >> 6;
    const int wcol = wv * 32;
    const int asw = (lrow & 7) << 4;

    const int gn = tid >> 2;
    const int gq = tid & 3;
    const int gnode = n0 + gn;
    const int grsw = (gn & 7) << 4;

    float comb[4][2][4];
#pragma unroll
    for (int rt = 0; rt < 4; ++rt)
#pragma unroll
        for (int ct = 0; ct < 2; ++ct)
#pragma unroll
            for (int j = 0; j < 4; ++j) {
                int node = n0 + rt * 16 + lk * 4 + j;
                int col = wcol + ct * 16 + lrow;
                comb[rt][ct][j] =
                    (node < N_NODES) ? bf2f(hinb[(size_t)node * HIDDEN + col]) : 0.f;
            }

    for (int r = 0; r < N_REL; ++r) {
        const unsigned short* aggr = agg + (size_t)r * N_NODES * HIDDEN;
#pragma unroll
        for (int i = 0; i < 4; ++i) {
            uint4 v = (gnode < N_NODES)
                          ? *((const uint4*)(aggr + (size_t)gnode * HIDDEN) + gq * 4 + i)
                          : uint4{0u, 0u, 0u, 0u};
            int byt = gn * 256 + ((gq * 64 + i * 16) ^ grsw);
            *(uint4*)((char*)atile_h + byt) = v;
        }
        __syncthreads();

        const unsigned short* Wh = WTbh + ((size_t)r << 14);
        const unsigned short* Wl = WTbl + ((size_t)r << 14);
        f32x4 macc[4][2];
#pragma unroll
        for (int rt = 0; rt < 4; ++rt) {
            macc[rt][0] = f32x4{0.f, 0.f, 0.f, 0.f};
            macc[rt][1] = f32x4{0.f, 0.f, 0.f, 0.f};
        }
#pragma unroll
        for (int kb = 0; kb < 4; ++kb) {
            int wo0 = (wcol + lrow) * HIDDEN + kb * 32 + lk * 8;
            int wo1 = (wcol + 16 + lrow) * HIDDEN + kb * 32 + lk * 8;
            short8 b0h = *(const short8*)(Wh + wo0);
            short8 b1h = *(const short8*)(Wh + wo1);
            short8 b0l = *(const short8*)(Wl + wo0);
            short8 b1l = *(const short8*)(Wl + wo1);
#pragma unroll
            for (int rt = 0; rt < 4; ++rt) {
                int ao = (rt * 16 + lrow) * 256 + ((kb * 64 + lk * 16) ^ asw);
                short8 ah = *(const short8*)((const char*)atile_h + ao);
                macc[rt][0] = __builtin_amdgcn_mfma_f32_16x16x32_bf16(ah, b0h, macc[rt][0], 0, 0, 0);
                macc[rt][0] = __builtin_amdgcn_mfma_f32_16x16x32_bf16(ah, b0l, macc[rt][0], 0, 0, 0);
                macc[rt][1] = __builtin_amdgcn_mfma_f32_16x16x32_bf16(ah, b1h, macc[rt][1], 0, 0, 0);
                macc[rt][1] = __builtin_amdgcn_mfma_f32_16x16x32_bf16(ah, b1l, macc[rt][1], 0, 0, 0);
            }
        }
#pragma unroll
        for (int rt = 0; rt < 4; ++rt)
#pragma unroll
            for (int ct = 0; ct < 2; ++ct)
#pragma unroll
                for (int j = 0; j < 4; ++j) comb[rt][ct][j] += ftanh(macc[rt][ct][j]);
        __syncthreads();
    }

#pragma unroll
    for (int rt = 0; rt < 4; ++rt)
#pragma unroll
        for (int ct = 0; ct < 2; ++ct)
#pragma unroll
            for (int j = 0; j < 4; ++j) {
                int row = rt * 16 + lk * 4 + j;
                int col = wcol + ct * 16 + lrow;
                int byt = row * 256 + ((col * 2) ^ ((row & 7) << 4));
                float x = comb[rt][ct][j];
                unsigned short hb = f2bf(x);
                *(unsigned short*)((char*)atile_h + byt) = hb;
                *(unsigned short*)((char*)atile_l + byt) = f2bf(x - bf2f(hb));
            }
    __syncthreads();

    f32x4 macc[4][2];
#pragma unroll
    for (int rt = 0; rt < 4; ++rt) {
        macc[rt][0] = f32x4{0.f, 0.f, 0.f, 0.f};
        macc[rt][1] = f32x4{0.f, 0.f, 0.f, 0.f};
    }
#pragma unroll
    for (int kb = 0; kb < 4; ++kb) {
        int wo0 = (wcol + lrow) * HIDDEN + kb * 32 + lk * 8;
        int wo1 = (wcol + 16 + lrow) * HIDDEN + kb * 32 + lk * 8;
        short8 b0h = *(const short8*)(WTch + wo0);
        short8 b1h = *(const short8*)(WTch + wo1);
        short8 b0l = *(const short8*)(WTcl + wo0);
        short8 b1l = *(const short8*)(WTcl + wo1);
#pragma unroll
        for (int rt = 0; rt < 4; ++rt) {
            int ao = (rt * 16 + lrow) * 256 + ((kb * 64 + lk * 16) ^ asw);
            short8 ah = *(const short8*)((const char*)atile_h + ao);
            short8 al = *(const short8*)((const char*)atile_l + ao);
            macc[rt][0] = __builtin_amdgcn_mfma_f32_16x16x32_bf16(ah, b0h, macc[rt][0], 0, 0, 0);
            macc[rt][0] = __builtin_amdgcn_mfma_f32_16x16x32_bf16(ah, b0l, macc[rt][0], 0, 0, 0);
            macc[rt][0] = __builtin_amdgcn_mfma_f32_16x16x32_bf16(al, b0h, macc[rt][0], 0, 0, 0);
            macc[rt][1] = __builtin_amdgcn_mfma_f32_16x16x32_bf16(ah, b1h, macc[rt][1], 0, 0, 0);
            macc[rt][1] = __builtin_amdgcn_mfma_f32_16x16x32_bf16(ah, b1l, macc[rt][1], 0, 0, 0);
            macc[rt][1] = __builtin_amdgcn_mfma_f32_16x16x32_bf16(al, b1h, macc[rt][1], 0, 0, 0);
        }
    }
#pragma unroll
    for (int rt = 0; rt < 4; ++rt)
#pragma unroll
        for (int ct = 0; ct < 2; ++ct)
#pragma unroll
            for (int j = 0; j < 4; ++j) {
                int node = n0 + rt * 16 + lk * 4 + j;
                if (node < N_NODES)
                    houtb[(size_t)node * HIDDEN + wcol + ct * 16 + lrow] =
                        f2bf(ftanh(macc[rt][ct][j]));
            }
}

// ---- out[j] = sum_n h[n][j] (bf16 in, f32 out) ----
__global__ void reduce_kernel(const unsigned short* __restrict__ h, float* __restrict__ out) {
    int j = threadIdx.x;
    float s = 0.f;
    for (int n = blockIdx.x; n < N_NODES; n += gridDim.x)
        s += bf2f(h[(size_t)n * HIDDEN + j]);
    atomicAdd(&out[j], s);
}

extern "C" void kernel_launch(void* const* d_in, const int* in_sizes, int n_in,
                              void* d_out, int out_size, void* d_ws, size_t ws_size,
                              hipStream_t stream) {
    const int* ei = (const int*)d_in[0];
    const float* Win = (const float*)d_in[1];
    const float* Wbr = (const float*)d_in[2];
    const float* Wcb = (const float*)d_in[3];
    float* out = (float*)d_out;

    char* p = (char*)d_ws;
    auto alloc = [&](size_t bytes) {
        char* q = p;
        p += (bytes + 511) & ~(size_t)511;
        return q;
    };
    int* cnt = (int*)alloc((size_t)N_REL * N_NODES * 4);
    int* rowptr = (int*)alloc((size_t)N_REL * (N_NODES + 1) * 4);
    int* ssorted = (int*)alloc((size_t)N_REL * N_EDGES * 4);
    unsigned* staging = (unsigned*)alloc((size_t)N_REL * N_EDGES * 4);
    int* bh = (int*)alloc((size_t)N_REL * NBUCK * NBB * 4);
    int* btot = (int*)alloc((size_t)N_REL * NBUCK * 4);
    int* bbase = (int*)alloc((size_t)N_REL * (NBUCK + 1) * 4);
    unsigned short* WTh = (unsigned short*)alloc((size_t)15 * HIDDEN * HIDDEN * 2);
    unsigned short* WTl = (unsigned short*)alloc((size_t)15 * HIDDEN * HIDDEN * 2);
    unsigned short* hb0 = (unsigned short*)alloc((size_t)N_NODES * HIDDEN * 2);
    unsigned short* hb1 = (unsigned short*)alloc((size_t)N_NODES * HIDDEN * 2);
    unsigned short* agg = (unsigned short*)alloc((size_t)N_REL * N_NODES * HIDDEN * 2);

    // ---- CSR build (bucketed counting sort; also emits cnt = degrees) ----
    dim3 bg(NBB, N_REL);
    bin_hist<<<bg, 256, 0, stream>>>(ei, bh);
    dim3 sg(NBUCK, N_REL);
    bin_scan<<<sg, 256, 0, stream>>>(bh, btot);
    bin_base<<<1, 64, 0, stream>>>(btot, bbase, rowptr);
    bin_scatter<<<bg, 256, 0, stream>>>(ei, bh, bbase, staging);
    bucket_sort<<<sg, 512, 0, stream>>>(staging, bbase, rowptr, cnt, ssorted);

    // ---- weights + h0 ----
    prepw_kernel<<<(15 * HIDDEN * HIDDEN + 255) / 256, 256, 0, stream>>>(Wbr, Wcb, WTh, WTl);
    hinit_kernel<<<(N_NODES * 16 + 255) / 256, 256, 0, stream>>>(cnt, Win, hb0);

    // ---- layers: gather (per relation) + fused GEMM ----
    dim3 gg((N_NODES + 15) / 16, N_REL);
    int cgrid = (N_NODES + 63) / 64;
    unsigned short* hbio[2] = {hb0, hb1};
    for (int l = 0; l < N_LAYERS; ++l) {
        int a = l & 1, b = a ^ 1;
        gather_kernel<<<gg, 256, 0, stream>>>(rowptr, ssorted, hbio[a], agg);
        gemm_kernel<<<cgrid, 256, 0, stream>>>(
            agg, hbio[a], hbio[b],
            WTh + (size_t)(l * 4) * HIDDEN * HIDDEN, WTl + (size_t)(l * 4) * HIDDEN * HIDDEN,
            WTh + (size_t)(12 + l) * HIDDEN * HIDDEN, WTl + (size_t)(12 + l) * HIDDEN * HIDDEN);
    }
    unsigned short* hfin = hbio[N_LAYERS & 1];

    hipMemsetAsync(out, 0, HIDDEN * sizeof(float), stream);
    reduce_kernel<<<1024, HIDDEN, 0, stream>>>(hfin, out);
}